// Round 9
// baseline (693.783 us; speedup 1.0000x reference)
//
#include <hip/hip_runtime.h>
#include <hip/hip_bf16.h>
#include <math.h>

typedef __hip_bfloat16 bf16;
typedef __attribute__((ext_vector_type(8))) short short8;
typedef __attribute__((ext_vector_type(4))) short s16x4;
typedef __attribute__((ext_vector_type(4))) float f32x4;
typedef __attribute__((ext_vector_type(2))) float f32x2;

#define Bb 8
#define Nn 256
#define Hh 8
#define DEPTHd 4
#define BN 2048
#define RTOT 524288
#define RELB 8192          // RTOT/64 relation blocks
#define JB 32              // BN/64 joint blocks
#define PREPB 64           // weight-prep tail blocks folded into k_rel3 dispatch
#define XTS 136

// k_rel3 LDS layout (bytes) -- ROUND-3 PROVEN LAYOUT (237us core).
#define X_OFF 0            // [64][264] bf16 = 33792
#define BST_OFF 33792      // 16384 staging
#define SST_OFF 50176      // [64][4][2] f32 = 2048
#define SSF_OFF 52224      // [64][2] f32 = 512
#define SMEM_TOT 52736     // 3 blocks/CU
#define X2S 264
#define X3S 136

__device__ inline float toF(float v) { return v; }
__device__ inline float toF(bf16 v) { return __bfloat162float(v); }
__device__ inline void stF(float* p, float v) { *p = v; }
__device__ inline void stF(bf16* p, float v) { *p = __float2bfloat16(v); }

__device__ inline void gload16(const bf16* g, bf16* l) {
  __builtin_amdgcn_global_load_lds(
      (const __attribute__((address_space(1))) unsigned int*)g,
      (__attribute__((address_space(3))) unsigned int*)l, 16, 0, 0);
}

// =============== k_rel3: relation encoder + joint encoder (+LN1+QKV d0) + late prep ===============
// ROUND-3 STRUCTURE (proven; rounds 4/5/7 structural variants all lost).
// Blocks [0,RELB): relation -> attnR (3-layer MLP + LN-folded 1x1conv).
// [RELB,RELB+JB): joint encoder -> jf, then FUSED depth-0 LN1+QKV via the same
//   LN-fold trick (WqLN = ln1_g-scaled Wq; y = inv*(Wg.x - mu*sWq) + bWq). Row-local,
//   runs concurrently with rel blocks -> replaces the k_lnqkv<float> dispatch for free.
// [RELB+JB,..+PREPB): late weight prep (Wq d1-3 / Wp / Wm / Wd), consumed only
//   by later kernels; rides the dispatch tail.
__global__ __launch_bounds__(256) void k_rel3(
    const float* __restrict__ rin, const bf16* __restrict__ Wt1,
    const float* __restrict__ b1, const bf16* __restrict__ Wt2,
    const float* __restrict__ b2, const bf16* __restrict__ Wt3,
    const float* __restrict__ b3, const bf16* __restrict__ gWt,
    const float* __restrict__ sgW, const float* __restrict__ bconst,
    bf16* __restrict__ attnR, const float* __restrict__ jin,
    const bf16* __restrict__ Wj1, const float* __restrict__ jb1,
    const bf16* __restrict__ Wj2, const float* __restrict__ jb2,
    const bf16* __restrict__ Wj3, const float* __restrict__ jb3,
    float* __restrict__ jf,
    const bf16* __restrict__ WqLN, const float* __restrict__ sWq,
    const float* __restrict__ bWq, float* __restrict__ qkvb,
    const float* __restrict__ qkv_w, const float* __restrict__ proj_w,
    const float* __restrict__ mw1, const float* __restrict__ mw2,
    const float* __restrict__ dw1, const float* __restrict__ dw2,
    const float* __restrict__ dw3, bf16* __restrict__ Wq, bf16* __restrict__ Wp,
    bf16* __restrict__ Wm1, bf16* __restrict__ Wm2, bf16* __restrict__ Wd1,
    bf16* __restrict__ Wd2, bf16* __restrict__ Wd3) {
  const int t = threadIdx.x;

  // ---- late weight-prep tail blocks (no LDS, no barriers; return early) ----
  if (blockIdx.x >= RELB + JB) {
    const int stride = PREPB * 256;
    const int tid = (blockIdx.x - (RELB + JB)) * 256 + t;
    // Wq slices d=1..3 only (d0 handled via WqLN in early prep)
    for (int i = 49152 + tid; i < 4 * 49152; i += stride) {
      int d = i / 49152, rem = i - d * 49152;
      int n = rem >> 7, k = rem & 127;
      Wq[i] = __float2bfloat16(qkv_w[d * 49152 + k * 384 + n]);
    }
    for (int i = tid; i < 4 * 128 * 128; i += stride) {
      int d = i >> 14, rem = i & 16383;
      int n = rem >> 7, k = rem & 127;
      Wp[i] = __float2bfloat16(proj_w[d * 16384 + k * 128 + n]);
      Wm1[i] = __float2bfloat16(mw1[d * 16384 + k * 128 + n]);
      Wm2[i] = __float2bfloat16(mw2[d * 16384 + k * 128 + n]);
    }
    for (int i = tid; i < 256 * 128; i += stride) {
      int n = i >> 7, k = i & 127;
      Wd1[i] = __float2bfloat16(dw1[k * 256 + n]);
    }
    for (int i = tid; i < 512 * 256; i += stride) {
      int n = i >> 8, k = i & 255;
      Wd2[i] = __float2bfloat16(dw2[k * 512 + n]);
    }
    for (int i = tid; i < 128 * 512; i += stride) {
      int n = i >> 9, k = i & 511;
      Wd3[i] = __float2bfloat16(n < 90 ? dw3[k * 90 + n] : 0.f);
    }
    return;
  }

  __shared__ __align__(16) char smem[SMEM_TOT];
  bf16* x1 = (bf16*)(smem + X_OFF);
  bf16* x2 = (bf16*)(smem + X_OFF);   // alias (x1 dead after L2 loop)
  bf16* x3 = (bf16*)(smem + X_OFF);   // alias (x2 dead after L3 loop)
  bf16* Bst = (bf16*)(smem + BST_OFF);
  float* sstat = (float*)(smem + SST_OFF);
  float* sstatF = (float*)(smem + SSF_OFF);

  const int lane = t & 63, wv = t >> 6;
  const int lrow = lane & 15, quad = lane >> 4;
  const bool rel = blockIdx.x < RELB;

  const bf16* W1 = rel ? Wt1 : Wj1;
  const bf16* W2 = rel ? Wt2 : Wj2;
  const bf16* W3 = rel ? Wt3 : Wj3;
  const float* B1 = rel ? b1 : jb1;
  const float* B2v = rel ? b2 : jb2;

  // stage W2 k-strip [256 cols][32] (source-side swizzle, 64B rows)
  auto stage2 = [&](int k0) {
#pragma unroll
    for (int c = 0; c < 4; ++c) {
      int cg = wv * 64 + c * 16;
      int col = cg + (lane >> 2);
      int ch = (lane & 3) ^ ((col >> 1) & 3);
      gload16(&W2[(size_t)col * 256 + k0 + ch * 8], &Bst[cg * 32]);
    }
  };
  // stage W3 strip s: [128 cols][64 k] (source-side swizzle, 128B rows)
  auto stage3 = [&](int s) {
#pragma unroll
    for (int c = 0; c < 4; ++c) {
      int cg = wv * 32 + c * 8;
      int row = cg + (lane >> 3);
      int ch = (lane & 7) ^ (row & 7);
      gload16(&W3[(size_t)row * 256 + s * 64 + ch * 8], &Bst[cg * 64]);
    }
  };

  stage2(0);  // issue first W2 strip; latency hides under x1 production

  // ---- produce whole x1 (64 rows x 256) upfront; A-frags direct from global ----
  short8 a0;       // rel: 32-wide input (26 valid)
  short8 aj[3];    // joint: 96-wide input
  if (rel) {
    const long gr = (long)blockIdx.x * 64 + wv * 16 + lrow;
    const float* ap = &rin[gr * 26];
    float v[8];
    if (quad < 3) {
#pragma unroll
      for (int u = 0; u < 4; ++u) {
        f32x2 f = *(const f32x2*)(ap + quad * 8 + u * 2);
        v[u * 2] = f[0];
        v[u * 2 + 1] = f[1];
      }
    } else {
      f32x2 f = *(const f32x2*)(ap + 24);
      v[0] = f[0];
      v[1] = f[1];
#pragma unroll
      for (int u = 2; u < 8; ++u) v[u] = 0.f;
    }
    bf16 pk[8];
#pragma unroll
    for (int u = 0; u < 8; ++u) pk[u] = __float2bfloat16(v[u]);
    a0 = *(short8*)pk;
  } else {
    const long gj = (long)(blockIdx.x - RELB) * 64 + wv * 16 + lrow;
#pragma unroll
    for (int ks = 0; ks < 3; ++ks) {
      const float* ap = &jin[gj * 96 + ks * 32 + quad * 8];
      f32x4 f0 = *(const f32x4*)ap;
      f32x4 f1 = *(const f32x4*)(ap + 4);
      bf16 pk[8];
#pragma unroll
      for (int u = 0; u < 4; ++u) {
        pk[u] = __float2bfloat16(f0[u]);
        pk[u + 4] = __float2bfloat16(f1[u]);
      }
      aj[ks] = *(short8*)pk;
    }
  }
#pragma unroll 2
  for (int ks8 = 0; ks8 < 8; ++ks8) {
#pragma unroll
    for (int ct = 0; ct < 2; ++ct) {
      f32x4 x = {0.f, 0.f, 0.f, 0.f};
      if (rel) {
        short8 bw = *(const short8*)&W1[(ks8 * 32 + ct * 16 + lrow) * 32 + quad * 8];
        x = __builtin_amdgcn_mfma_f32_16x16x32_bf16(bw, a0, x, 0, 0, 0);
      } else {
#pragma unroll
        for (int ks = 0; ks < 3; ++ks) {
          short8 bw =
              *(const short8*)&W1[(ks8 * 32 + ct * 16 + lrow) * 96 + ks * 32 + quad * 8];
          x = __builtin_amdgcn_mfma_f32_16x16x32_bf16(bw, aj[ks], x, 0, 0, 0);
        }
      }
      f32x4 bq = *(const f32x4*)&B1[ks8 * 32 + ct * 16 + quad * 4];
      bf16 pk[4];
#pragma unroll
      for (int r = 0; r < 4; ++r) pk[r] = __float2bfloat16(x[r] + bq[r]);
      *(s16x4*)&x1[(wv * 16 + lrow) * X2S + ks8 * 32 + ct * 16 + quad * 4] =
          *(s16x4*)pk;
    }
  }

  // ---- L2 (K=256): pure consume+stage loop ----
  f32x4 acc2[4][4];
#pragma unroll
  for (int i = 0; i < 4; ++i)
#pragma unroll
    for (int j = 0; j < 4; ++j) {
      f32x4 z = {0.f, 0.f, 0.f, 0.f};
      acc2[i][j] = z;
    }
  __syncthreads();  // x1 visible + Bst(0) drained
  for (int k = 0; k < 8; ++k) {
    short8 af[4], bfr[4];
#pragma unroll
    for (int i = 0; i < 4; ++i)
      af[i] = *(const short8*)&x1[(i * 16 + lrow) * X2S + k * 32 + quad * 8];
#pragma unroll
    for (int j = 0; j < 4; ++j) {
      int rb = wv * 64 + j * 16 + lrow;
      bfr[j] = *(const short8*)&Bst[rb * 32 + ((quad ^ ((rb >> 1) & 3)) * 8)];
    }
#pragma unroll
    for (int i = 0; i < 4; ++i)
#pragma unroll
      for (int j = 0; j < 4; ++j)
        acc2[i][j] =
            __builtin_amdgcn_mfma_f32_16x16x32_bf16(bfr[j], af[i], acc2[i][j], 0, 0, 0);
    __syncthreads();
    if (k < 7) {
      stage2((k + 1) * 32);
      __syncthreads();
    }
  }

  // write x2 from acc2 (aliases x1: all x1 reads done at loop's final barrier)
  {
#pragma unroll
    for (int i = 0; i < 4; ++i)
#pragma unroll
      for (int j = 0; j < 4; ++j) {
        f32x4 bq = *(const f32x4*)&B2v[wv * 64 + j * 16 + quad * 4];
        bf16 pk[4];
#pragma unroll
        for (int r = 0; r < 4; ++r) pk[r] = __float2bfloat16(acc2[i][j][r] + bq[r]);
        *(s16x4*)&x2[(i * 16 + lrow) * X2S + wv * 64 + j * 16 + quad * 4] =
            *(s16x4*)pk;
      }
    stage3(0);
  }
  __syncthreads();

  // ---- L3 (K=256, 128 cols): wave = 64 rows x 32 cols ----
  f32x4 acc3[4][2];
#pragma unroll
  for (int i = 0; i < 4; ++i) {
    f32x4 z = {0.f, 0.f, 0.f, 0.f};
    acc3[i][0] = z;
    acc3[i][1] = z;
  }
  for (int s = 0; s < 4; ++s) {
#pragma unroll
    for (int kk = 0; kk < 2; ++kk) {
      short8 af[4], bfr[2];
#pragma unroll
      for (int i = 0; i < 4; ++i)
        af[i] =
            *(const short8*)&x2[(i * 16 + lrow) * X2S + s * 64 + kk * 32 + quad * 8];
#pragma unroll
      for (int j = 0; j < 2; ++j) {
        int rb = wv * 32 + j * 16 + lrow;
        bfr[j] = *(const short8*)&Bst[rb * 64 + (((kk * 4 + quad) ^ (rb & 7)) * 8)];
      }
#pragma unroll
      for (int i = 0; i < 4; ++i)
#pragma unroll
        for (int j = 0; j < 2; ++j)
          acc3[i][j] =
              __builtin_amdgcn_mfma_f32_16x16x32_bf16(bfr[j], af[i], acc3[i][j], 0, 0, 0);
    }
    __syncthreads();
    if (s < 3) {
      stage3(s + 1);
      __syncthreads();
    }
  }

  const float* B3v = rel ? b3 : jb3;

  if (!rel) {
    // ---- joint: jf store + LN stats (raw values; LN folded into QKV weights) ----
    const long r0j = (long)(blockIdx.x - RELB) * 64;
#pragma unroll
    for (int i = 0; i < 4; ++i) {
      float s1 = 0.f, s2v = 0.f;
#pragma unroll
      for (int j = 0; j < 2; ++j) {
        f32x4 bq = *(const f32x4*)&B3v[wv * 32 + j * 16 + quad * 4];
        f32x4 out;
#pragma unroll
        for (int r = 0; r < 4; ++r) {
          out[r] = acc3[i][j][r] + bq[r];
          s1 += out[r];
          s2v += out[r] * out[r];
        }
        *(f32x4*)&jf[(r0j + i * 16 + lrow) * 128 + wv * 32 + j * 16 + quad * 4] = out;
      }
      s1 += __shfl_xor(s1, 16, 64);
      s2v += __shfl_xor(s2v, 16, 64);
      s1 += __shfl_xor(s1, 32, 64);
      s2v += __shfl_xor(s2v, 32, 64);
      if (quad == 0) {
        int row = i * 16 + lrow;
        sstat[(row * 4 + wv) * 2] = s1;
        sstat[(row * 4 + wv) * 2 + 1] = s2v;
      }
    }
    __syncthreads();  // all x2 reads done (x3 aliases x2) + stats visible

    // x3 raw write (bf16, packed b64)
#pragma unroll
    for (int i = 0; i < 4; ++i)
#pragma unroll
      for (int j = 0; j < 2; ++j) {
        f32x4 bq = *(const f32x4*)&B3v[wv * 32 + j * 16 + quad * 4];
        bf16 pk[4];
#pragma unroll
        for (int r = 0; r < 4; ++r) pk[r] = __float2bfloat16(acc3[i][j][r] + bq[r]);
        *(s16x4*)&x3[(i * 16 + lrow) * X3S + wv * 32 + j * 16 + quad * 4] =
            *(s16x4*)pk;
      }
    if (t < 64) {
      float s1 = 0.f, s2v = 0.f;
#pragma unroll
      for (int w = 0; w < 4; ++w) {
        s1 += sstat[(t * 4 + w) * 2];
        s2v += sstat[(t * 4 + w) * 2 + 1];
      }
      float mu = s1 * (1.f / 128.f);
      float var = s2v * (1.f / 128.f) - mu * mu;
      sstatF[t * 2] = mu;
      sstatF[t * 2 + 1] = rsqrtf(var + 1e-5f);
    }
    __syncthreads();  // x3 + sstatF visible

    // ---- depth-0 QKV: 64 rows x 384 cols, K=128; wave n-split 96 ----
    f32x4 acc4[4][6];
#pragma unroll
    for (int i = 0; i < 4; ++i)
#pragma unroll
      for (int j = 0; j < 6; ++j) {
        f32x4 z = {0.f, 0.f, 0.f, 0.f};
        acc4[i][j] = z;
      }
#pragma unroll
    for (int k0 = 0; k0 < 128; k0 += 32) {
      short8 af[4], bfr[6];
#pragma unroll
      for (int i = 0; i < 4; ++i)
        af[i] = *(const short8*)&x3[(i * 16 + lrow) * X3S + k0 + quad * 8];
#pragma unroll
      for (int j = 0; j < 6; ++j)
        bfr[j] = *(const short8*)&WqLN[(long)(wv * 96 + j * 16 + lrow) * 128 + k0 +
                                       quad * 8];
#pragma unroll
      for (int i = 0; i < 4; ++i)
#pragma unroll
        for (int j = 0; j < 6; ++j)
          acc4[i][j] =
              __builtin_amdgcn_mfma_f32_16x16x32_bf16(af[i], bfr[j], acc4[i][j], 0, 0, 0);
    }
#pragma unroll
    for (int i = 0; i < 4; ++i)
#pragma unroll
      for (int r = 0; r < 4; ++r) {
        int rl = i * 16 + quad * 4 + r;
        long gr = r0j + rl;
        float mu = sstatF[rl * 2], inv = sstatF[rl * 2 + 1];
#pragma unroll
        for (int j = 0; j < 6; ++j) {
          int gc = wv * 96 + j * 16 + lrow;
          qkvb[gr * 384 + gc] = inv * (acc4[i][j][r] - mu * sWq[gc]) + bWq[gc];
        }
      }
    return;
  }

  // ---- rel: x3 write (alias x2, packed b64) + LN stats (2 shfl per i) ----
#pragma unroll
  for (int i = 0; i < 4; ++i) {
    float s1 = 0.f, s2 = 0.f;
#pragma unroll
    for (int j = 0; j < 2; ++j) {
      f32x4 bq = *(const f32x4*)&b3[wv * 32 + j * 16 + quad * 4];
      bf16 pk[4];
#pragma unroll
      for (int r = 0; r < 4; ++r) {
        float v = acc3[i][j][r] + bq[r];
        pk[r] = __float2bfloat16(v);
        s1 += v;
        s2 += v * v;
      }
      *(s16x4*)&x3[(i * 16 + lrow) * X3S + wv * 32 + j * 16 + quad * 4] = *(s16x4*)pk;
    }
    s1 += __shfl_xor(s1, 16, 64);
    s2 += __shfl_xor(s2, 16, 64);
    s1 += __shfl_xor(s1, 32, 64);
    s2 += __shfl_xor(s2, 32, 64);
    if (quad == 0) {
      int row = i * 16 + lrow;
      sstat[(row * 4 + wv) * 2] = s1;
      sstat[(row * 4 + wv) * 2 + 1] = s2;
    }
  }
  // hoist gemm32 A-operands (gWt, L1/L2-hot) across stats barriers
  short8 aw0[4], aw1[4];
#pragma unroll
  for (int kk = 0; kk < 4; ++kk) {
    aw0[kk] = *(const short8*)&gWt[lrow * 128 + kk * 32 + quad * 8];
    aw1[kk] = *(const short8*)&gWt[(16 + lrow) * 128 + kk * 32 + quad * 8];
  }
  __syncthreads();
  if (t < 64) {
    float s1 = 0.f, s2 = 0.f;
#pragma unroll
    for (int w = 0; w < 4; ++w) {
      s1 += sstat[(t * 4 + w) * 2];
      s2 += sstat[(t * 4 + w) * 2 + 1];
    }
    float mu = s1 * (1.f / 128.f);
    float var = s2 * (1.f / 128.f) - mu * mu;
    sstatF[t * 2] = mu;
    sstatF[t * 2 + 1] = rsqrtf(var + 1e-5f);
  }
  __syncthreads();

  // ---- gemm32: 32 out-chans x 64 rows (wave = 16 rows), LN stats trick, scatter ----
  {
    f32x4 ac0 = {0.f, 0.f, 0.f, 0.f}, ac1 = {0.f, 0.f, 0.f, 0.f};
#pragma unroll
    for (int kk = 0; kk < 4; ++kk) {
      short8 bbx = *(const short8*)&x3[(wv * 16 + lrow) * X3S + kk * 32 + quad * 8];
      ac0 = __builtin_amdgcn_mfma_f32_16x16x32_bf16(aw0[kk], bbx, ac0, 0, 0, 0);
      ac1 = __builtin_amdgcn_mfma_f32_16x16x32_bf16(aw1[kk], bbx, ac1, 0, 0, 0);
    }
    const long r0 = (long)blockIdx.x * 64;
    int drow = wv * 16 + lrow;
    long gr = r0 + drow;
    float mu = sstatF[drow * 2], inv = sstatF[drow * 2 + 1];
    int bb_ = (int)(gr >> 16);
    int nn = (int)((gr >> 8) & 255);
    int mm = (int)(gr & 255);
#pragma unroll
    for (int mt = 0; mt < 2; ++mt) {
      f32x4 a = mt ? ac1 : ac0;
#pragma unroll
      for (int reg = 0; reg < 4; ++reg) {
        int col = mt * 16 + quad * 4 + reg;
        float v = inv * (a[reg] - mu * sgW[col]) + bconst[col];
        int dd = col >> 3, hh = col & 7;
        attnR[((((long)dd * Bb + bb_) * Hh + hh) * Nn + nn) * Nn + mm] =
            __float2bfloat16(v);
      }
    }
  }
}

// =============== k_dec: final LN -> d1(256) -> d2(512) -> d3(90), fully fused ===============
// Row-local chain: each block owns 32 rows end-to-end. LDS-staged u1/u2 tiles,
// direct-global B operands (L2-hot). Replaces k_lnqkv<bf16> + 2x k_gemm_mfma.
__global__ __launch_bounds__(256) void k_dec(
    const float* __restrict__ jf, const float* __restrict__ ng,
    const float* __restrict__ nb, const bf16* __restrict__ Wd1,
    const float* __restrict__ db1, const bf16* __restrict__ Wd2,
    const float* __restrict__ db2, const bf16* __restrict__ Wd3,
    const float* __restrict__ db3, float* __restrict__ out) {
  // sU2 [32][520] @0 (33280) | sU1 [32][264] @33280 (16896) | sX [32][136] @50176 (8704)
  __shared__ __align__(16) char smem[58880];
  bf16* sU2 = (bf16*)smem;
  bf16* sU1 = (bf16*)(smem + 33280);
  bf16* sX = (bf16*)(smem + 50176);
  const int t = threadIdx.x;
  const int lane = t & 63, wv = t >> 6;
  const int lrow = lane & 15, quad = lane >> 4;
  const long row0 = (long)blockIdx.x * 32;

  // ---- phase 1: final LN (dim 128) -> sX bf16 ----
  {
    int row = t >> 3, prt = t & 7;
    const float* ap = &jf[(row0 + row) * 128 + prt * 16];
    float v[16];
    float s1 = 0.f, s2 = 0.f;
#pragma unroll
    for (int u = 0; u < 4; ++u) {
      f32x4 q = *(const f32x4*)(ap + u * 4);
#pragma unroll
      for (int e = 0; e < 4; ++e) {
        v[u * 4 + e] = q[e];
        s1 += q[e];
        s2 += q[e] * q[e];
      }
    }
    s1 += __shfl_xor(s1, 1, 64);
    s2 += __shfl_xor(s2, 1, 64);
    s1 += __shfl_xor(s1, 2, 64);
    s2 += __shfl_xor(s2, 2, 64);
    s1 += __shfl_xor(s1, 4, 64);
    s2 += __shfl_xor(s2, 4, 64);
    float mu = s1 * (1.f / 128.f);
    float inv = rsqrtf(s2 * (1.f / 128.f) - mu * mu + 1e-5f);
#pragma unroll
    for (int u4 = 0; u4 < 4; ++u4) {
      bf16 pk[4];
#pragma unroll
      for (int e = 0; e < 4; ++e) {
        int c = prt * 16 + u4 * 4 + e;
        pk[e] = __float2bfloat16((v[u4 * 4 + e] - mu) * inv * ng[c] + nb[c]);
      }
      *(s16x4*)&sX[row * XTS + prt * 16 + u4 * 4] = *(s16x4*)pk;
    }
  }
  __syncthreads();

  // ---- phase 2: d1 (K=128 -> 256 cols) -> sU1 ----
  {
    f32x4 a1[2][4];
#pragma unroll
    for (int i = 0; i < 2; ++i)
#pragma unroll
      for (int j = 0; j < 4; ++j) {
        f32x4 z = {0.f, 0.f, 0.f, 0.f};
        a1[i][j] = z;
      }
#pragma unroll
    for (int k0 = 0; k0 < 128; k0 += 32) {
      short8 af[2], bfr[4];
#pragma unroll
      for (int i = 0; i < 2; ++i)
        af[i] = *(const short8*)&sX[(i * 16 + lrow) * XTS + k0 + quad * 8];
#pragma unroll
      for (int j = 0; j < 4; ++j)
        bfr[j] = *(const short8*)&Wd1[(wv * 64 + j * 16 + lrow) * 128 + k0 + quad * 8];
#pragma unroll
      for (int i = 0; i < 2; ++i)
#pragma unroll
        for (int j = 0; j < 4; ++j)
          a1[i][j] =
              __builtin_amdgcn_mfma_f32_16x16x32_bf16(af[i], bfr[j], a1[i][j], 0, 0, 0);
    }
#pragma unroll
    for (int i = 0; i < 2; ++i)
#pragma unroll
      for (int r = 0; r < 4; ++r) {
        int rl = i * 16 + quad * 4 + r;
#pragma unroll
        for (int j = 0; j < 4; ++j) {
          int gc = wv * 64 + j * 16 + lrow;
          sU1[rl * 264 + gc] = __float2bfloat16(a1[i][j][r] + db1[gc]);
        }
      }
  }
  __syncthreads();

  // ---- phase 3: d2 (K=256 -> 512 cols) -> sU2 ----
  {
    f32x4 a2[2][8];
#pragma unroll
    for (int i = 0; i < 2; ++i)
#pragma unroll
      for (int j = 0; j < 8; ++j) {
        f32x4 z = {0.f, 0.f, 0.f, 0.f};
        a2[i][j] = z;
      }
#pragma unroll
    for (int k0 = 0; k0 < 256; k0 += 32) {
      short8 af[2], bfr[8];
#pragma unroll
      for (int i = 0; i < 2; ++i)
        af[i] = *(const short8*)&sU1[(i * 16 + lrow) * 264 + k0 + quad * 8];
#pragma unroll
      for (int j = 0; j < 8; ++j)
        bfr[j] =
            *(const short8*)&Wd2[(wv * 128 + j * 16 + lrow) * 256 + k0 + quad * 8];
#pragma unroll
      for (int i = 0; i < 2; ++i)
#pragma unroll
        for (int j = 0; j < 8; ++j)
          a2[i][j] =
              __builtin_amdgcn_mfma_f32_16x16x32_bf16(af[i], bfr[j], a2[i][j], 0, 0, 0);
    }
#pragma unroll
    for (int i = 0; i < 2; ++i)
#pragma unroll
      for (int r = 0; r < 4; ++r) {
        int rl = i * 16 + quad * 4 + r;
#pragma unroll
        for (int j = 0; j < 8; ++j) {
          int gc = wv * 128 + j * 16 + lrow;
          sU2[rl * 520 + gc] = __float2bfloat16(a2[i][j][r] + db2[gc]);
        }
      }
  }
  __syncthreads();

  // ---- phase 4: d3 (K=512 -> 90 cols) -> out ----
  {
    f32x4 a3[2][2];
#pragma unroll
    for (int i = 0; i < 2; ++i)
#pragma unroll
      for (int j = 0; j < 2; ++j) {
        f32x4 z = {0.f, 0.f, 0.f, 0.f};
        a3[i][j] = z;
      }
#pragma unroll
    for (int k0 = 0; k0 < 512; k0 += 32) {
      short8 af[2], bfr[2];
#pragma unroll
      for (int i = 0; i < 2; ++i)
        af[i] = *(const short8*)&sU2[(i * 16 + lrow) * 520 + k0 + quad * 8];
#pragma unroll
      for (int j = 0; j < 2; ++j)
        bfr[j] =
            *(const short8*)&Wd3[(wv * 32 + j * 16 + lrow) * 512 + k0 + quad * 8];
#pragma unroll
      for (int i = 0; i < 2; ++i)
#pragma unroll
        for (int j = 0; j < 2; ++j)
          a3[i][j] =
              __builtin_amdgcn_mfma_f32_16x16x32_bf16(af[i], bfr[j], a3[i][j], 0, 0, 0);
    }
#pragma unroll
    for (int i = 0; i < 2; ++i)
#pragma unroll
      for (int r = 0; r < 4; ++r) {
        long gr = row0 + i * 16 + quad * 4 + r;
#pragma unroll
        for (int j = 0; j < 2; ++j) {
          int gc = wv * 32 + j * 16 + lrow;
          if (gc < 90) out[gr * 90 + gc] = a3[i][j][r] + db3[gc];
        }
      }
  }
}

// =============== k_tailq: proj+resid -> LN3 -> MLP(+gelu) -> resid [-> LN1' + QKV'] ===============
// 16-row blocks (grid 128).
template <bool QKV>
__global__ __launch_bounds__(256) void k_tailq(
    const bf16* __restrict__ obuf, float* __restrict__ jf, const bf16* __restrict__ Wp,
    const float* __restrict__ pb, const float* __restrict__ g3,
    const float* __restrict__ b3, const bf16* __restrict__ Wm1,
    const float* __restrict__ m1b, const bf16* __restrict__ Wm2,
    const float* __restrict__ m2b, const float* __restrict__ g1n,
    const float* __restrict__ b1n, const bf16* __restrict__ Wqn,
    const float* __restrict__ qbn, float* __restrict__ qkvb) {
  __shared__ __align__(16) bf16 sX[16 * XTS];
  __shared__ __align__(16) bf16 sH[16 * XTS];
  __shared__ float sstat[16][4][2];
  __shared__ float sstatF[16][2];

  const int t = threadIdx.x;
  const int lane = t & 63;
  const int wv = t >> 6;
  const int lrow = lane & 15, quad = lane >> 4;
  const long row0 = (long)blockIdx.x * 16;

  {
    int r = t >> 4, c8 = (t & 15) * 8;
    *(uint4*)&sX[r * XTS + c8] = *(const uint4*)&obuf[(row0 + r) * 128 + c8];
  }
  __syncthreads();

  // ---- proj GEMM (16x128, K=128), wave n-split 32 ----
  f32x4 acc[2];
  {
    f32x4 z = {0.f, 0.f, 0.f, 0.f};
    acc[0] = z;
    acc[1] = z;
  }
#pragma unroll
  for (int k0 = 0; k0 < 128; k0 += 32) {
    short8 af = *(const short8*)&sX[lrow * XTS + k0 + quad * 8];
    short8 bfr[2];
#pragma unroll
    for (int j = 0; j < 2; ++j)
      bfr[j] = *(const short8*)&Wp[(wv * 32 + j * 16 + lrow) * 128 + k0 + quad * 8];
#pragma unroll
    for (int j = 0; j < 2; ++j)
      acc[j] = __builtin_amdgcn_mfma_f32_16x16x32_bf16(af, bfr[j], acc[j], 0, 0, 0);
  }
#pragma unroll
  for (int r = 0; r < 4; ++r) {
    int rl = quad * 4 + r;
    long gr = row0 + rl;
    float s1 = 0.f, s2 = 0.f;
#pragma unroll
    for (int j = 0; j < 2; ++j) {
      int gc = wv * 32 + j * 16 + lrow;
      float v = acc[j][r] + pb[gc] + jf[gr * 128 + gc];
      acc[j][r] = v;
      jf[gr * 128 + gc] = v;
      s1 += v;
      s2 += v * v;
    }
#pragma unroll
    for (int m = 1; m < 16; m <<= 1) {
      s1 += __shfl_xor(s1, m, 64);
      s2 += __shfl_xor(s2, m, 64);
    }
    if (lrow == 0) {
      sstat[rl][wv][0] = s1;
      sstat[rl][wv][1] = s2;
    }
  }
  __syncthreads();
  if (t < 16) {
    float s1 = 0.f, s2 = 0.f;
#pragma unroll
    for (int w = 0; w < 4; ++w) {
      s1 += sstat[t][w][0];
      s2 += sstat[t][w][1];
    }
    float mu = s1 * (1.f / 128.f);
    float var = s2 * (1.f / 128.f) - mu * mu;
    sstatF[t][0] = mu;
    sstatF[t][1] = rsqrtf(var + 1e-5f);
  }
  __syncthreads();
#pragma unroll
  for (int r = 0; r < 4; ++r) {
    int rl = quad * 4 + r;
    float mu = sstatF[rl][0], inv = sstatF[rl][1];
#pragma unroll
    for (int j = 0; j < 2; ++j) {
      int gc = wv * 32 + j * 16 + lrow;
      sX[rl * XTS + gc] = __float2bfloat16((acc[j][r] - mu) * inv * g3[gc] + b3[gc]);
    }
  }
  __syncthreads();

  // ---- MLP1 + gelu ----
  f32x4 acc2[2];
  {
    f32x4 z = {0.f, 0.f, 0.f, 0.f};
    acc2[0] = z;
    acc2[1] = z;
  }
#pragma unroll
  for (int k0 = 0; k0 < 128; k0 += 32) {
    short8 af = *(const short8*)&sX[lrow * XTS + k0 + quad * 8];
    short8 bfr[2];
#pragma unroll
    for (int j = 0; j < 2; ++j)
      bfr[j] = *(const short8*)&Wm1[(wv * 32 + j * 16 + lrow) * 128 + k0 + quad * 8];
#pragma unroll
    for (int j = 0; j < 2; ++j)
      acc2[j] = __builtin_amdgcn_mfma_f32_16x16x32_bf16(af, bfr[j], acc2[j], 0, 0, 0);
  }
#pragma unroll
  for (int r = 0; r < 4; ++r) {
    int rl = quad * 4 + r;
#pragma unroll
    for (int j = 0; j < 2; ++j) {
      int gc = wv * 32 + j * 16 + lrow;
      float v = acc2[j][r] + m1b[gc];
      v = 0.5f * v * (1.f + erff(v * 0.70710678118654752f));
      sH[rl * XTS + gc] = __float2bfloat16(v);
    }
  }
  __syncthreads();

  // ---- MLP2 + resid [+ stats] ----
  f32x4 acc3[2];
  {
    f32x4 z = {0.f, 0.f, 0.f, 0.f};
    acc3[0] = z;
    acc3[1] = z;
  }
#pragma unroll
  for (int k0 = 0; k0 < 128; k0 += 32) {
    short8 af = *(const short8*)&sH[lrow * XTS + k0 + quad * 8];
    short8 bfr[2];
#pragma unroll
    for (int j = 0; j < 2; ++j)
      bfr[j] = *(const short8*)&Wm2[(wv * 32 + j * 16 + lrow) * 128 + k0 + quad * 8];
#pragma unroll
    for (int j = 0; j < 2; ++j)
      acc3[j] = __builtin_amdgcn_mfma_f32_16x16x32_bf16(af, bfr[j], acc3[j], 0, 0, 0);
  }
#pragma unroll
  for (int r = 0; r < 4; ++r) {
    int rl = quad * 4 + r;
    long gr = row0 + rl;
    float s1 = 0.f, s2 = 0.f;
#pragma unroll
    for (int j = 0; j < 2; ++j) {
      int gc = wv * 32 + j * 16 + lrow;
      float v = acc3[j][r] + m2b[gc] + jf[gr * 128 + gc];
      acc3[j][r] = v;
      jf[gr * 128 + gc] = v;
      if (QKV) {
        s1 += v;
        s2 += v * v;
      }
    }
    if (QKV) {
#pragma unroll
      for (int m = 1; m < 16; m <<= 1) {
        s1 += __shfl_xor(s1, m, 64);
        s2 += __shfl_xor(s2, m, 64);
      }
      if (lrow == 0) {
        sstat[rl][wv][0] = s1;
        sstat[rl][wv][1] = s2;
      }
    }
  }
  if (!QKV) return;
  __syncthreads();
  if (t < 16) {
    float s1 = 0.f, s2 = 0.f;
#pragma unroll
    for (int w = 0; w < 4; ++w) {
      s1 += sstat[t][w][0];
      s2 += sstat[t][w][1];
    }
    float mu = s1 * (1.f / 128.f);
    float var = s2 * (1.f / 128.f) - mu * mu;
    sstatF[t][0] = mu;
    sstatF[t][1] = rsqrtf(var + 1e-5f);
  }
  __syncthreads();
#pragma unroll
  for (int r = 0; r < 4; ++r) {
    int rl = quad * 4 + r;
    float mu = sstatF[rl][0], inv = sstatF[rl][1];
#pragma unroll
    for (int j = 0; j < 2; ++j) {
      int gc = wv * 32 + j * 16 + lrow;
      sX[rl * XTS + gc] = __float2bfloat16((acc3[j][r] - mu) * inv * g1n[gc] + b1n[gc]);
    }
  }
  __syncthreads();
  for (int p = 0; p < 3; ++p) {
    f32x4 acc4[2];
    {
      f32x4 z = {0.f, 0.f, 0.f, 0.f};
      acc4[0] = z;
      acc4[1] = z;
    }
#pragma unroll
    for (int k0 = 0; k0 < 128; k0 += 32) {
      short8 af = *(const short8*)&sX[lrow * XTS + k0 + quad * 8];
      short8 bfr[2];
#pragma unroll
      for (int j = 0; j < 2; ++j)
        bfr[j] = *(const short8*)&Wqn[(long)(p * 128 + wv * 32 + j * 16 + lrow) * 128 +
                                      k0 + quad * 8];
#pragma unroll
      for (int j = 0; j < 2; ++j)
        acc4[j] = __builtin_amdgcn_mfma_f32_16x16x32_bf16(af, bfr[j], acc4[j], 0, 0, 0);
    }
#pragma unroll
    for (int r = 0; r < 4; ++r) {
      long gr = row0 + quad * 4 + r;
#pragma unroll
      for (int j = 0; j < 2; ++j) {
        int gc = p * 128 + wv * 32 + j * 16 + lrow;
        qkvb[gr * 384 + gc] = acc4[j][r] + qbn[gc];
      }
    }
  }
}

// ---- prep (EARLY): weights for k_rel3 + LN-folded depth-0 QKV (WqLN/sWq/bWq) ----
__global__ void k_prep(const float* re_w1, const float* re_w2, const float* re_w3,
                       const float* ln2_g, const float* ln2_b, const float* rconv_w,
                       const float* rconv_b, const float* je_w1, const float* je_w2,
                       const float* je_w3, const float* qkv_w, const float* qkv_b,
                       const float* ln1_g, const float* ln1_b, bf16* Wt1, bf16* Wt2,
                       bf16* Wt3, bf16* gWt, float* sgW, float* bconst, bf16* Wj1,
                       bf16* Wj2, bf16* Wj3, bf16* WqLN, float* sWq, float* bWq) {
  const int stride = gridDim.x * blockDim.x;
  const int tid = blockIdx.x * blockDim.x + threadIdx.x;
  for (int i = tid; i < 256 * 32; i += stride) {
    int n = i >> 5, k = i & 31;
    Wt1[i] = __float2bfloat16(k < 26 ? re_w1[k * 256 + n] : 0.f);
  }
  for (int i = tid; i < 256 * 256; i += stride) {
    int n = i >> 8, k = i & 255;
    Wt2[i] = __float2bfloat16(re_w2[k * 256 + n]);
  }
  for (int i = tid; i < 128 * 256; i += stride) {
    int n = i >> 8, k = i & 255;
    Wt3[i] = __float2bfloat16(re_w3[k * 128 + n]);
  }
  for (int i = tid; i < 32 * 128; i += stride) {
    int col = i >> 7, c = i & 127;
    int dd = col >> 3, h = col & 7;
    gWt[i] = __float2bfloat16(ln2_g[dd * 128 + c] * rconv_w[(dd * 128 + c) * 8 + h]);
  }
  if (tid < 32) {
    int dd = tid >> 3, h = tid & 7;
    float sg = 0.f, bc = 0.f;
    for (int c = 0; c < 128; ++c) {
      float w = rconv_w[(dd * 128 + c) * 8 + h];
      sg += ln2_g[dd * 128 + c] * w;
      bc += ln2_b[dd * 128 + c] * w;
    }
    sgW[tid] = sg;
    bconst[tid] = bc + rconv_b[tid];
  }
  for (int i = tid; i < 256 * 96; i += stride) {
    int n = i / 96, k = i - n * 96;
    Wj1[i] = __float2bfloat16(je_w1[k * 256 + n]);
  }
  for (int i = tid; i < 256 * 256; i += stride) {
    int n = i >> 8, k = i & 255;
    Wj2[i] = __float2bfloat16(je_w2[k * 256 + n]);
  }
  for (int i = tid; i < 128 * 256; i += stride) {
    int n = i >> 8, k = i & 255;
    Wj3[i] = __float2bfloat16(je_w3[k * 128 + n]);
  }
  // LN-folded depth-0 QKV weight: WqLN[col][k] = ln1_g[0][k] * qkv_w[0][k][col]
  for (int i = tid; i < 384 * 128; i += stride) {
    int n = i >> 7, k = i & 127;
    WqLN[i] = __float2bfloat16(ln1_g[k] * qkv_w[k * 384 + n]);
  }
  if (tid < 384) {
    float sw = 0.f, bw = 0.f;
    for (int k = 0; k < 128; ++k) {
      float w = qkv_w[k * 384 + tid];
      sw += ln1_g[k] * w;
      bw += ln1_b[k] * w;
    }
    sWq[tid] = sw;
    bWq[tid] = bw + qkv_b[tid];
  }
}

// ---- fused attention: 4 independent waves per block, one wave per (b,h,n) ----
__global__ __launch_bounds__(256) void k_attn(const float* __restrict__ qkv,
                                              const bf16* __restrict__ aR,
                                              const float* __restrict__ conn,
                                              bf16* __restrict__ obuf) {
  __shared__ float p[4][4 * 68];
  const int wv = threadIdx.x >> 6;
  const int n = blockIdx.x * 4 + wv;
  const int h = blockIdx.y, b = blockIdx.z;
  const int lane = threadIdx.x & 63;
  const long rowq = (long)(b * Nn + n);
  const float* qp = &qkv[rowq * 384 + h * 16];
  f32x4 q0 = *(const f32x4*)qp;
  f32x4 q1 = *(const f32x4*)(qp + 4);
  f32x4 q2 = *(const f32x4*)(qp + 8);
  f32x4 q3 = *(const f32x4*)(qp + 12);
  const bf16* arp = &aR[((long)(b * Hh + h) * Nn + n) * Nn];
  const float* cnp = &conn[rowq * Nn];

  float lg[4];
#pragma unroll
  for (int s = 0; s < 4; ++s) {
    int m = s * 64 + lane;
    const float* kp = &qkv[((long)(b * Nn + m)) * 384 + 128 + h * 16];
    f32x4 k0 = *(const f32x4*)kp;
    f32x4 k1 = *(const f32x4*)(kp + 4);
    f32x4 k2 = *(const f32x4*)(kp + 8);
    f32x4 k3 = *(const f32x4*)(kp + 12);
    float d = 0.f;
#pragma unroll
    for (int e = 0; e < 4; ++e)
      d += q0[e] * k0[e] + q1[e] * k1[e] + q2[e] * k2[e] + q3[e] * k3[e];
    d += __bfloat162float(arp[m]);
    lg[s] = d * cnp[m] * 0.25f;
  }
  float mx = fmaxf(fmaxf(lg[0], lg[1]), fmaxf(lg[2], lg[3]));
#pragma unroll
  for (int off = 32; off; off >>= 1) mx = fmaxf(mx, __shfl_xor(mx, off, 64));
  float ex[4], ssum = 0.f;
#pragma unroll
  for (int s = 0; s < 4; ++s) {
    ex[s] = expf(lg[s] - mx);
    ssum += ex[s];
  }
#pragma unroll
  for (int off = 32; off; off >>= 1) ssum += __shfl_xor(ssum, off, 64);
#pragma unroll
  for (int s = 0; s < 4; ++s) p[wv][s * 68 + lane] = ex[s];
  float rinv = 1.f / ssum;

  const int c = lane & 15, sg = lane >> 4;
  const float* vp = &qkv[((long)(b * Nn + sg * 64)) * 384 + 256 + h * 16 + c];
  float acc = 0.f;
#pragma unroll
  for (int u = 0; u < 16; ++u) {
    f32x4 pq = *(const f32x4*)&p[wv][sg * 68 + u * 4];
#pragma unroll
    for (int e = 0; e < 4; ++e) acc += pq[e] * vp[(long)(u * 4 + e) * 384];
  }
  acc += __shfl_xor(acc, 16, 64);
  acc += __shfl_xor(acc, 32, 64);
  if (lane < 16) obuf[rowq * 128 + h * 16 + lane] = __float2bfloat16(acc * rinv);
}

extern "C" void kernel_launch(void* const* d_in, const int* in_sizes, int n_in,
                              void* d_out, int out_size, void* d_ws, size_t ws_size,
                              hipStream_t stream) {
  const float* joint_in = (const float*)d_in[0];
  const float* relation_in = (const float*)d_in[1];
  const float* conn = (const float*)d_in[2];
  const float* je_w1 = (const float*)d_in[3];
  const float* je_b1 = (const float*)d_in[4];
  const float* je_w2 = (const float*)d_in[5];
  const float* je_b2 = (const float*)d_in[6];
  const float* je_w3 = (const float*)d_in[7];
  const float* je_b3 = (const float*)d_in[8];
  const float* re_w1 = (const float*)d_in[9];
  const float* re_b1 = (const float*)d_in[10];
  const float* re_w2 = (const float*)d_in[11];
  const float* re_b2 = (const float*)d_in[12];
  const float* re_w3 = (const float*)d_in[13];
  const float* re_b3 = (const float*)d_in[14];
  const float* qkv_w = (const float*)d_in[15];
  const float* qkv_b = (const float*)d_in[16];
  const float* rconv_w = (const float*)d_in[17];
  const float* rconv_b = (const float*)d_in[18];
  const float* proj_w = (const float*)d_in[19];
  const float* proj_b = (const float*)d_in[20];
  const float* ln1_g = (const float*)d_in[21];
  const float* ln1_b = (const float*)d_in[22];
  const float* ln2_g = (const float*)d_in[23];
  const float* ln2_b = (const float*)d_in[24];
  const float* ln3_g = (const float*)d_in[25];
  const float* ln3_b = (const float*)d_in[26];
  const float* mw1 = (const float*)d_in[27];
  const float* mb1 = (const float*)d_in[28];
  const float* mw2 = (const float*)d_in[29];
  const float* mb2 = (const float*)d_in[30];
  const float* ng = (const float*)d_in[31];
  const float* nb = (const float*)d_in[32];
  const float* dw1 = (const float*)d_in[33];
  const float* db1 = (const float*)d_in[34];
  const float* dw2 = (const float*)d_in[35];
  const float* db2 = (const float*)d_in[36];
  const float* dw3 = (const float*)d_in[37];
  const float* db3 = (const float*)d_in[38];

  char* ws = (char*)d_ws;
  size_t off = 0;
  auto alloc = [&](size_t bytes) -> void* {
    void* p = ws + off;
    off += (bytes + 255) & ~(size_t)255;
    return p;
  };
  bf16* attnR = (bf16*)alloc((size_t)DEPTHd * Bb * Hh * Nn * Nn * 2);
  bf16* Wt1 = (bf16*)alloc(256 * 32 * 2);
  bf16* Wt2 = (bf16*)alloc(256 * 256 * 2);
  bf16* Wt3 = (bf16*)alloc(128 * 256 * 2);
  bf16* gWt = (bf16*)alloc(32 * 128 * 2);
  float* sgW = (float*)alloc(32 * 4);
  float* bconst = (float*)alloc(32 * 4);
  bf16* Wj1 = (bf16*)alloc(256 * 96 * 2);
  bf16* Wj2 = (bf16*)alloc(256 * 256 * 2);
  bf16* Wj3 = (bf16*)alloc(128 * 256 * 2);
  bf16* Wq = (bf16*)alloc(4 * 384 * 128 * 2);
  bf16* Wp = (bf16*)alloc(4 * 128 * 128 * 2);
  bf16* Wm1 = (bf16*)alloc(4 * 128 * 128 * 2);
  bf16* Wm2 = (bf16*)alloc(4 * 128 * 128 * 2);
  bf16* Wd1 = (bf16*)alloc(256 * 128 * 2);
  bf16* Wd2 = (bf16*)alloc(512 * 256 * 2);
  bf16* Wd3 = (bf16*)alloc(128 * 512 * 2);
  bf16* WqLN = (bf16*)alloc(384 * 128 * 2);
  float* sWq = (float*)alloc(384 * 4);
  float* bWq = (float*)alloc(384 * 4);
  float* jf = (float*)alloc((size_t)BN * 128 * 4);
  bf16* obuf = (bf16*)alloc((size_t)BN * 128 * 2);
  char* U = (char*)alloc((size_t)BN * 384 * 4);
  float* qkvb = (float*)U;

  // early prep: k_rel3's weights + LN-folded depth-0 QKV
  k_prep<<<dim3(256), dim3(256), 0, stream>>>(
      re_w1, re_w2, re_w3, ln2_g, ln2_b, rconv_w, rconv_b, je_w1, je_w2, je_w3,
      qkv_w, qkv_b, ln1_g, ln1_b, Wt1, Wt2, Wt3, gWt, sgW, bconst, Wj1, Wj2, Wj3,
      WqLN, sWq, bWq);

  // relation encoder (attnR) + joint encoder (jf + depth-0 QKV) + late weight prep
  k_rel3<<<dim3(RELB + JB + PREPB), dim3(256), 0, stream>>>(
      relation_in, Wt1, re_b1, Wt2, re_b2, Wt3, re_b3, gWt, sgW, bconst, attnR,
      joint_in, Wj1, je_b1, Wj2, je_b2, Wj3, je_b3, jf, WqLN, sWq, bWq, qkvb,
      qkv_w, proj_w, mw1, mw2, dw1, dw2, dw3, Wq, Wp, Wm1, Wm2, Wd1, Wd2, Wd3);

  for (int d = 0; d < DEPTHd; ++d) {
    k_attn<<<dim3(Nn / 4, Hh, Bb), dim3(256), 0, stream>>>(
        qkvb, attnR + (size_t)d * Bb * Hh * Nn * Nn, conn, obuf);
    if (d < 3) {
      k_tailq<true><<<dim3(128), dim3(256), 0, stream>>>(
          obuf, jf, Wp + (size_t)d * 16384, proj_b + d * 128, ln3_g + d * 128,
          ln3_b + d * 128, Wm1 + (size_t)d * 16384, mb1 + d * 128,
          Wm2 + (size_t)d * 16384, mb2 + d * 128, ln1_g + (d + 1) * 128,
          ln1_b + (d + 1) * 128, Wq + (size_t)(d + 1) * 49152, qkv_b + (d + 1) * 384,
          qkvb);
    } else {
      k_tailq<false><<<dim3(128), dim3(256), 0, stream>>>(
          obuf, jf, Wp + (size_t)d * 16384, proj_b + d * 128, ln3_g + d * 128,
          ln3_b + d * 128, Wm1 + (size_t)d * 16384, mb1 + d * 128,
          Wm2 + (size_t)d * 16384, mb2 + d * 128, nullptr, nullptr, nullptr, nullptr,
          nullptr);
    }
  }

  // fused final LN + decoder (256 -> 512 -> 90)
  k_dec<<<dim3(64), dim3(256), 0, stream>>>(jf, ng, nb, Wd1, db1, Wd2, db2, Wd3, db3,
                                            (float*)d_out);
}

// Round 10
// 642.719 us; speedup vs baseline: 1.0795x; 1.0795x over previous
//
#include <hip/hip_runtime.h>
#include <hip/hip_bf16.h>
#include <math.h>

typedef __hip_bfloat16 bf16;
typedef __attribute__((ext_vector_type(8))) short short8;
typedef __attribute__((ext_vector_type(4))) short s16x4;
typedef __attribute__((ext_vector_type(4))) float f32x4;
typedef __attribute__((ext_vector_type(2))) float f32x2;

#define Bb 8
#define Nn 256
#define Hh 8
#define DEPTHd 4
#define BN 2048
#define RTOT 524288
#define RELB 8192          // RTOT/64 relation blocks
#define JB 32              // BN/64 joint blocks
#define PREPB 64           // weight-prep tail blocks folded into k_rel3 dispatch
#define XTS 136

// k_rel3 LDS layout (bytes) -- ROUND-3 PROVEN LAYOUT (237us core).
#define X_OFF 0            // [64][264] bf16 = 33792
#define BST_OFF 33792      // 16384 staging
#define SST_OFF 50176      // [64][4][2] f32 = 2048
#define SSF_OFF 52224      // [64][2] f32 = 512
#define SMEM_TOT 52736     // 3 blocks/CU
#define X2S 264
#define X3S 136

__device__ inline float toF(float v) { return v; }
__device__ inline float toF(bf16 v) { return __bfloat162float(v); }
__device__ inline void stF(float* p, float v) { *p = v; }
__device__ inline void stF(bf16* p, float v) { *p = __float2bfloat16(v); }

__device__ inline void gload16(const bf16* g, bf16* l) {
  __builtin_amdgcn_global_load_lds(
      (const __attribute__((address_space(1))) unsigned int*)g,
      (__attribute__((address_space(3))) unsigned int*)l, 16, 0, 0);
}

// =============== k_rel3: relation encoder + joint encoder + late weight prep ===============
// ROUND-8 VERSION VERBATIM (VGPR 80, 252us incl. tail -- proven). Round 9's
// joint-branch QKV fusion pushed VGPR 80->128 kernel-wide (acc4[4][6]) and cost
// the 8192 rel blocks ~45us: REGISTER ALLOCATION IS PER-KERNEL, fusions must not
// add register pressure to the hot branch.
// Blocks [0,RELB): relation -> attnR. [RELB,RELB+JB): joint encoder -> jf.
// [RELB+JB,..+PREPB): late weight prep (Wq/Wp/Wm/Wd) rides the dispatch tail.
__global__ __launch_bounds__(256) void k_rel3(
    const float* __restrict__ rin, const bf16* __restrict__ Wt1,
    const float* __restrict__ b1, const bf16* __restrict__ Wt2,
    const float* __restrict__ b2, const bf16* __restrict__ Wt3,
    const float* __restrict__ b3, const bf16* __restrict__ gWt,
    const float* __restrict__ sgW, const float* __restrict__ bconst,
    bf16* __restrict__ attnR, const float* __restrict__ jin,
    const bf16* __restrict__ Wj1, const float* __restrict__ jb1,
    const bf16* __restrict__ Wj2, const float* __restrict__ jb2,
    const bf16* __restrict__ Wj3, const float* __restrict__ jb3,
    float* __restrict__ jf,
    const float* __restrict__ qkv_w, const float* __restrict__ proj_w,
    const float* __restrict__ mw1, const float* __restrict__ mw2,
    const float* __restrict__ dw1, const float* __restrict__ dw2,
    const float* __restrict__ dw3, bf16* __restrict__ Wq, bf16* __restrict__ Wp,
    bf16* __restrict__ Wm1, bf16* __restrict__ Wm2, bf16* __restrict__ Wd1,
    bf16* __restrict__ Wd2, bf16* __restrict__ Wd3) {
  const int t = threadIdx.x;

  // ---- late weight-prep tail blocks (no LDS, no barriers; return early) ----
  if (blockIdx.x >= RELB + JB) {
    const int stride = PREPB * 256;
    const int tid = (blockIdx.x - (RELB + JB)) * 256 + t;
    for (int i = tid; i < 4 * 384 * 128; i += stride) {
      int d = i / 49152, rem = i - d * 49152;
      int n = rem >> 7, k = rem & 127;
      Wq[i] = __float2bfloat16(qkv_w[d * 49152 + k * 384 + n]);
    }
    for (int i = tid; i < 4 * 128 * 128; i += stride) {
      int d = i >> 14, rem = i & 16383;
      int n = rem >> 7, k = rem & 127;
      Wp[i] = __float2bfloat16(proj_w[d * 16384 + k * 128 + n]);
      Wm1[i] = __float2bfloat16(mw1[d * 16384 + k * 128 + n]);
      Wm2[i] = __float2bfloat16(mw2[d * 16384 + k * 128 + n]);
    }
    for (int i = tid; i < 256 * 128; i += stride) {
      int n = i >> 7, k = i & 127;
      Wd1[i] = __float2bfloat16(dw1[k * 256 + n]);
    }
    for (int i = tid; i < 512 * 256; i += stride) {
      int n = i >> 8, k = i & 255;
      Wd2[i] = __float2bfloat16(dw2[k * 512 + n]);
    }
    for (int i = tid; i < 128 * 512; i += stride) {
      int n = i >> 9, k = i & 511;
      Wd3[i] = __float2bfloat16(n < 90 ? dw3[k * 90 + n] : 0.f);
    }
    return;
  }

  __shared__ __align__(16) char smem[SMEM_TOT];
  bf16* x1 = (bf16*)(smem + X_OFF);
  bf16* x2 = (bf16*)(smem + X_OFF);   // alias (x1 dead after L2 loop)
  bf16* x3 = (bf16*)(smem + X_OFF);   // alias (x2 dead after L3 loop)
  bf16* Bst = (bf16*)(smem + BST_OFF);
  float* sstat = (float*)(smem + SST_OFF);
  float* sstatF = (float*)(smem + SSF_OFF);

  const int lane = t & 63, wv = t >> 6;
  const int lrow = lane & 15, quad = lane >> 4;
  const bool rel = blockIdx.x < RELB;

  const bf16* W1 = rel ? Wt1 : Wj1;
  const bf16* W2 = rel ? Wt2 : Wj2;
  const bf16* W3 = rel ? Wt3 : Wj3;
  const float* B1 = rel ? b1 : jb1;
  const float* B2v = rel ? b2 : jb2;

  // stage W2 k-strip [256 cols][32] (source-side swizzle, 64B rows)
  auto stage2 = [&](int k0) {
#pragma unroll
    for (int c = 0; c < 4; ++c) {
      int cg = wv * 64 + c * 16;
      int col = cg + (lane >> 2);
      int ch = (lane & 3) ^ ((col >> 1) & 3);
      gload16(&W2[(size_t)col * 256 + k0 + ch * 8], &Bst[cg * 32]);
    }
  };
  // stage W3 strip s: [128 cols][64 k] (source-side swizzle, 128B rows)
  auto stage3 = [&](int s) {
#pragma unroll
    for (int c = 0; c < 4; ++c) {
      int cg = wv * 32 + c * 8;
      int row = cg + (lane >> 3);
      int ch = (lane & 7) ^ (row & 7);
      gload16(&W3[(size_t)row * 256 + s * 64 + ch * 8], &Bst[cg * 64]);
    }
  };

  stage2(0);  // issue first W2 strip; latency hides under x1 production

  // ---- produce whole x1 (64 rows x 256) upfront; A-frags direct from global ----
  short8 a0;       // rel: 32-wide input (26 valid)
  short8 aj[3];    // joint: 96-wide input
  if (rel) {
    const long gr = (long)blockIdx.x * 64 + wv * 16 + lrow;
    const float* ap = &rin[gr * 26];
    float v[8];
    if (quad < 3) {
#pragma unroll
      for (int u = 0; u < 4; ++u) {
        f32x2 f = *(const f32x2*)(ap + quad * 8 + u * 2);
        v[u * 2] = f[0];
        v[u * 2 + 1] = f[1];
      }
    } else {
      f32x2 f = *(const f32x2*)(ap + 24);
      v[0] = f[0];
      v[1] = f[1];
#pragma unroll
      for (int u = 2; u < 8; ++u) v[u] = 0.f;
    }
    bf16 pk[8];
#pragma unroll
    for (int u = 0; u < 8; ++u) pk[u] = __float2bfloat16(v[u]);
    a0 = *(short8*)pk;
  } else {
    const long gj = (long)(blockIdx.x - RELB) * 64 + wv * 16 + lrow;
#pragma unroll
    for (int ks = 0; ks < 3; ++ks) {
      const float* ap = &jin[gj * 96 + ks * 32 + quad * 8];
      f32x4 f0 = *(const f32x4*)ap;
      f32x4 f1 = *(const f32x4*)(ap + 4);
      bf16 pk[8];
#pragma unroll
      for (int u = 0; u < 4; ++u) {
        pk[u] = __float2bfloat16(f0[u]);
        pk[u + 4] = __float2bfloat16(f1[u]);
      }
      aj[ks] = *(short8*)pk;
    }
  }
#pragma unroll 2
  for (int ks8 = 0; ks8 < 8; ++ks8) {
#pragma unroll
    for (int ct = 0; ct < 2; ++ct) {
      f32x4 x = {0.f, 0.f, 0.f, 0.f};
      if (rel) {
        short8 bw = *(const short8*)&W1[(ks8 * 32 + ct * 16 + lrow) * 32 + quad * 8];
        x = __builtin_amdgcn_mfma_f32_16x16x32_bf16(bw, a0, x, 0, 0, 0);
      } else {
#pragma unroll
        for (int ks = 0; ks < 3; ++ks) {
          short8 bw =
              *(const short8*)&W1[(ks8 * 32 + ct * 16 + lrow) * 96 + ks * 32 + quad * 8];
          x = __builtin_amdgcn_mfma_f32_16x16x32_bf16(bw, aj[ks], x, 0, 0, 0);
        }
      }
      f32x4 bq = *(const f32x4*)&B1[ks8 * 32 + ct * 16 + quad * 4];
      bf16 pk[4];
#pragma unroll
      for (int r = 0; r < 4; ++r) pk[r] = __float2bfloat16(x[r] + bq[r]);
      *(s16x4*)&x1[(wv * 16 + lrow) * X2S + ks8 * 32 + ct * 16 + quad * 4] =
          *(s16x4*)pk;
    }
  }

  // ---- L2 (K=256): pure consume+stage loop ----
  f32x4 acc2[4][4];
#pragma unroll
  for (int i = 0; i < 4; ++i)
#pragma unroll
    for (int j = 0; j < 4; ++j) {
      f32x4 z = {0.f, 0.f, 0.f, 0.f};
      acc2[i][j] = z;
    }
  __syncthreads();  // x1 visible + Bst(0) drained
  for (int k = 0; k < 8; ++k) {
    short8 af[4], bfr[4];
#pragma unroll
    for (int i = 0; i < 4; ++i)
      af[i] = *(const short8*)&x1[(i * 16 + lrow) * X2S + k * 32 + quad * 8];
#pragma unroll
    for (int j = 0; j < 4; ++j) {
      int rb = wv * 64 + j * 16 + lrow;
      bfr[j] = *(const short8*)&Bst[rb * 32 + ((quad ^ ((rb >> 1) & 3)) * 8)];
    }
#pragma unroll
    for (int i = 0; i < 4; ++i)
#pragma unroll
      for (int j = 0; j < 4; ++j)
        acc2[i][j] =
            __builtin_amdgcn_mfma_f32_16x16x32_bf16(bfr[j], af[i], acc2[i][j], 0, 0, 0);
    __syncthreads();
    if (k < 7) {
      stage2((k + 1) * 32);
      __syncthreads();
    }
  }

  // write x2 from acc2 (aliases x1: all x1 reads done at loop's final barrier)
  {
#pragma unroll
    for (int i = 0; i < 4; ++i)
#pragma unroll
      for (int j = 0; j < 4; ++j) {
        f32x4 bq = *(const f32x4*)&B2v[wv * 64 + j * 16 + quad * 4];
        bf16 pk[4];
#pragma unroll
        for (int r = 0; r < 4; ++r) pk[r] = __float2bfloat16(acc2[i][j][r] + bq[r]);
        *(s16x4*)&x2[(i * 16 + lrow) * X2S + wv * 64 + j * 16 + quad * 4] =
            *(s16x4*)pk;
      }
    stage3(0);
  }
  __syncthreads();

  // ---- L3 (K=256, 128 cols): wave = 64 rows x 32 cols ----
  f32x4 acc3[4][2];
#pragma unroll
  for (int i = 0; i < 4; ++i) {
    f32x4 z = {0.f, 0.f, 0.f, 0.f};
    acc3[i][0] = z;
    acc3[i][1] = z;
  }
  for (int s = 0; s < 4; ++s) {
#pragma unroll
    for (int kk = 0; kk < 2; ++kk) {
      short8 af[4], bfr[2];
#pragma unroll
      for (int i = 0; i < 4; ++i)
        af[i] =
            *(const short8*)&x2[(i * 16 + lrow) * X2S + s * 64 + kk * 32 + quad * 8];
#pragma unroll
      for (int j = 0; j < 2; ++j) {
        int rb = wv * 32 + j * 16 + lrow;
        bfr[j] = *(const short8*)&Bst[rb * 64 + (((kk * 4 + quad) ^ (rb & 7)) * 8)];
      }
#pragma unroll
      for (int i = 0; i < 4; ++i)
#pragma unroll
        for (int j = 0; j < 2; ++j)
          acc3[i][j] =
              __builtin_amdgcn_mfma_f32_16x16x32_bf16(bfr[j], af[i], acc3[i][j], 0, 0, 0);
    }
    __syncthreads();
    if (s < 3) {
      stage3(s + 1);
      __syncthreads();
    }
  }

  if (!rel) {
    const long r0j = (long)(blockIdx.x - RELB) * 64;
#pragma unroll
    for (int i = 0; i < 4; ++i)
#pragma unroll
      for (int j = 0; j < 2; ++j) {
        f32x4 bq = *(const f32x4*)&jb3[wv * 32 + j * 16 + quad * 4];
        f32x4 out;
#pragma unroll
        for (int r = 0; r < 4; ++r) out[r] = acc3[i][j][r] + bq[r];
        *(f32x4*)&jf[(r0j + i * 16 + lrow) * 128 + wv * 32 + j * 16 + quad * 4] = out;
      }
    return;
  }

  // ---- rel: x3 write (alias x2, packed b64) + LN stats (2 shfl per i) ----
#pragma unroll
  for (int i = 0; i < 4; ++i) {
    float s1 = 0.f, s2 = 0.f;
#pragma unroll
    for (int j = 0; j < 2; ++j) {
      f32x4 bq = *(const f32x4*)&b3[wv * 32 + j * 16 + quad * 4];
      bf16 pk[4];
#pragma unroll
      for (int r = 0; r < 4; ++r) {
        float v = acc3[i][j][r] + bq[r];
        pk[r] = __float2bfloat16(v);
        s1 += v;
        s2 += v * v;
      }
      *(s16x4*)&x3[(i * 16 + lrow) * X3S + wv * 32 + j * 16 + quad * 4] = *(s16x4*)pk;
    }
    s1 += __shfl_xor(s1, 16, 64);
    s2 += __shfl_xor(s2, 16, 64);
    s1 += __shfl_xor(s1, 32, 64);
    s2 += __shfl_xor(s2, 32, 64);
    if (quad == 0) {
      int row = i * 16 + lrow;
      sstat[(row * 4 + wv) * 2] = s1;
      sstat[(row * 4 + wv) * 2 + 1] = s2;
    }
  }
  // hoist gemm32 A-operands (gWt, L1/L2-hot) across stats barriers
  short8 aw0[4], aw1[4];
#pragma unroll
  for (int kk = 0; kk < 4; ++kk) {
    aw0[kk] = *(const short8*)&gWt[lrow * 128 + kk * 32 + quad * 8];
    aw1[kk] = *(const short8*)&gWt[(16 + lrow) * 128 + kk * 32 + quad * 8];
  }
  __syncthreads();
  if (t < 64) {
    float s1 = 0.f, s2 = 0.f;
#pragma unroll
    for (int w = 0; w < 4; ++w) {
      s1 += sstat[(t * 4 + w) * 2];
      s2 += sstat[(t * 4 + w) * 2 + 1];
    }
    float mu = s1 * (1.f / 128.f);
    float var = s2 * (1.f / 128.f) - mu * mu;
    sstatF[t * 2] = mu;
    sstatF[t * 2 + 1] = rsqrtf(var + 1e-5f);
  }
  __syncthreads();

  // ---- gemm32: 32 out-chans x 64 rows (wave = 16 rows), LN stats trick, scatter ----
  {
    f32x4 ac0 = {0.f, 0.f, 0.f, 0.f}, ac1 = {0.f, 0.f, 0.f, 0.f};
#pragma unroll
    for (int kk = 0; kk < 4; ++kk) {
      short8 bbx = *(const short8*)&x3[(wv * 16 + lrow) * X3S + kk * 32 + quad * 8];
      ac0 = __builtin_amdgcn_mfma_f32_16x16x32_bf16(aw0[kk], bbx, ac0, 0, 0, 0);
      ac1 = __builtin_amdgcn_mfma_f32_16x16x32_bf16(aw1[kk], bbx, ac1, 0, 0, 0);
    }
    const long r0 = (long)blockIdx.x * 64;
    int drow = wv * 16 + lrow;
    long gr = r0 + drow;
    float mu = sstatF[drow * 2], inv = sstatF[drow * 2 + 1];
    int bb_ = (int)(gr >> 16);
    int nn = (int)((gr >> 8) & 255);
    int mm = (int)(gr & 255);
#pragma unroll
    for (int mt = 0; mt < 2; ++mt) {
      f32x4 a = mt ? ac1 : ac0;
#pragma unroll
      for (int reg = 0; reg < 4; ++reg) {
        int col = mt * 16 + quad * 4 + reg;
        float v = inv * (a[reg] - mu * sgW[col]) + bconst[col];
        int dd = col >> 3, hh = col & 7;
        attnR[((((long)dd * Bb + bb_) * Hh + hh) * Nn + nn) * Nn + mm] =
            __float2bfloat16(v);
      }
    }
  }
}

// =============== k_lnqkv: row-LN (dim 128) fused into K=128 GEMM, 32-row blocks ===============
template <typename TC>
__global__ __launch_bounds__(256) void k_lnqkv(
    const float* __restrict__ A, const float* __restrict__ g,
    const float* __restrict__ b, const bf16* __restrict__ Bt,
    const float* __restrict__ bias, TC* __restrict__ C, int ldc, int ncols) {
  __shared__ __align__(16) bf16 sX[32 * XTS];
  const int t = threadIdx.x;
  const int lane = t & 63;
  const int wv = t >> 6;
  const int lrow = lane & 15, quad = lane >> 4;
  const long row0 = (long)blockIdx.y * 32;
  const int n0 = blockIdx.x * 128;

  {
    int row = t >> 3, prt = t & 7;
    const float* ap = &A[(row0 + row) * 128 + prt * 16];
    float v[16];
    float s1 = 0.f, s2 = 0.f;
#pragma unroll
    for (int u = 0; u < 4; ++u) {
      f32x4 q = *(const f32x4*)(ap + u * 4);
#pragma unroll
      for (int e = 0; e < 4; ++e) {
        v[u * 4 + e] = q[e];
        s1 += q[e];
        s2 += q[e] * q[e];
      }
    }
    s1 += __shfl_xor(s1, 1, 64);
    s2 += __shfl_xor(s2, 1, 64);
    s1 += __shfl_xor(s1, 2, 64);
    s2 += __shfl_xor(s2, 2, 64);
    s1 += __shfl_xor(s1, 4, 64);
    s2 += __shfl_xor(s2, 4, 64);
    float mu = s1 * (1.f / 128.f);
    float inv = rsqrtf(s2 * (1.f / 128.f) - mu * mu + 1e-5f);
#pragma unroll
    for (int u4 = 0; u4 < 4; ++u4) {
      bf16 pk[4];
#pragma unroll
      for (int e = 0; e < 4; ++e) {
        int c = prt * 16 + u4 * 4 + e;
        pk[e] = __float2bfloat16((v[u4 * 4 + e] - mu) * inv * g[c] + b[c]);
      }
      *(s16x4*)&sX[row * XTS + prt * 16 + u4 * 4] = *(s16x4*)pk;
    }
  }
  __syncthreads();

  f32x4 acc[2][2];
#pragma unroll
  for (int i = 0; i < 2; ++i)
#pragma unroll
    for (int j = 0; j < 2; ++j) {
      f32x4 z = {0.f, 0.f, 0.f, 0.f};
      acc[i][j] = z;
    }
#pragma unroll
  for (int k0 = 0; k0 < 128; k0 += 32) {
    short8 af[2], bfr[2];
#pragma unroll
    for (int j = 0; j < 2; ++j)
      bfr[j] = *(const short8*)&Bt[(long)(n0 + wv * 32 + j * 16 + lrow) * 128 + k0 +
                                   quad * 8];
#pragma unroll
    for (int i = 0; i < 2; ++i)
      af[i] = *(const short8*)&sX[(i * 16 + lrow) * XTS + k0 + quad * 8];
#pragma unroll
    for (int i = 0; i < 2; ++i)
#pragma unroll
      for (int j = 0; j < 2; ++j)
        acc[i][j] =
            __builtin_amdgcn_mfma_f32_16x16x32_bf16(af[i], bfr[j], acc[i][j], 0, 0, 0);
  }
#pragma unroll
  for (int i = 0; i < 2; ++i) {
#pragma unroll
    for (int r = 0; r < 4; ++r) {
      long gr = row0 + i * 16 + quad * 4 + r;
#pragma unroll
      for (int j = 0; j < 2; ++j) {
        int gc = n0 + wv * 32 + j * 16 + lrow;
        if (gc < ncols) stF(&C[gr * (long)ldc + gc], acc[i][j][r] + bias[gc]);
      }
    }
  }
}

// =============== k_dec: final LN -> d1(256) -> d2(512) -> d3(90), fully fused ===============
// Row-local chain: each block owns 32 rows end-to-end (R9-proven, kept).
__global__ __launch_bounds__(256) void k_dec(
    const float* __restrict__ jf, const float* __restrict__ ng,
    const float* __restrict__ nb, const bf16* __restrict__ Wd1,
    const float* __restrict__ db1, const bf16* __restrict__ Wd2,
    const float* __restrict__ db2, const bf16* __restrict__ Wd3,
    const float* __restrict__ db3, float* __restrict__ out) {
  // sU2 [32][520] @0 (33280) | sU1 [32][264] @33280 (16896) | sX [32][136] @50176 (8704)
  __shared__ __align__(16) char smem[58880];
  bf16* sU2 = (bf16*)smem;
  bf16* sU1 = (bf16*)(smem + 33280);
  bf16* sX = (bf16*)(smem + 50176);
  const int t = threadIdx.x;
  const int lane = t & 63, wv = t >> 6;
  const int lrow = lane & 15, quad = lane >> 4;
  const long row0 = (long)blockIdx.x * 32;

  // ---- phase 1: final LN (dim 128) -> sX bf16 ----
  {
    int row = t >> 3, prt = t & 7;
    const float* ap = &jf[(row0 + row) * 128 + prt * 16];
    float v[16];
    float s1 = 0.f, s2 = 0.f;
#pragma unroll
    for (int u = 0; u < 4; ++u) {
      f32x4 q = *(const f32x4*)(ap + u * 4);
#pragma unroll
      for (int e = 0; e < 4; ++e) {
        v[u * 4 + e] = q[e];
        s1 += q[e];
        s2 += q[e] * q[e];
      }
    }
    s1 += __shfl_xor(s1, 1, 64);
    s2 += __shfl_xor(s2, 1, 64);
    s1 += __shfl_xor(s1, 2, 64);
    s2 += __shfl_xor(s2, 2, 64);
    s1 += __shfl_xor(s1, 4, 64);
    s2 += __shfl_xor(s2, 4, 64);
    float mu = s1 * (1.f / 128.f);
    float inv = rsqrtf(s2 * (1.f / 128.f) - mu * mu + 1e-5f);
#pragma unroll
    for (int u4 = 0; u4 < 4; ++u4) {
      bf16 pk[4];
#pragma unroll
      for (int e = 0; e < 4; ++e) {
        int c = prt * 16 + u4 * 4 + e;
        pk[e] = __float2bfloat16((v[u4 * 4 + e] - mu) * inv * ng[c] + nb[c]);
      }
      *(s16x4*)&sX[row * XTS + prt * 16 + u4 * 4] = *(s16x4*)pk;
    }
  }
  __syncthreads();

  // ---- phase 2: d1 (K=128 -> 256 cols) -> sU1 ----
  {
    f32x4 a1[2][4];
#pragma unroll
    for (int i = 0; i < 2; ++i)
#pragma unroll
      for (int j = 0; j < 4; ++j) {
        f32x4 z = {0.f, 0.f, 0.f, 0.f};
        a1[i][j] = z;
      }
#pragma unroll
    for (int k0 = 0; k0 < 128; k0 += 32) {
      short8 af[2], bfr[4];
#pragma unroll
      for (int i = 0; i < 2; ++i)
        af[i] = *(const short8*)&sX[(i * 16 + lrow) * XTS + k0 + quad * 8];
#pragma unroll
      for (int j = 0; j < 4; ++j)
        bfr[j] = *(const short8*)&Wd1[(wv * 64 + j * 16 + lrow) * 128 + k0 + quad * 8];
#pragma unroll
      for (int i = 0; i < 2; ++i)
#pragma unroll
        for (int j = 0; j < 4; ++j)
          a1[i][j] =
              __builtin_amdgcn_mfma_f32_16x16x32_bf16(af[i], bfr[j], a1[i][j], 0, 0, 0);
    }
#pragma unroll
    for (int i = 0; i < 2; ++i)
#pragma unroll
      for (int r = 0; r < 4; ++r) {
        int rl = i * 16 + quad * 4 + r;
#pragma unroll
        for (int j = 0; j < 4; ++j) {
          int gc = wv * 64 + j * 16 + lrow;
          sU1[rl * 264 + gc] = __float2bfloat16(a1[i][j][r] + db1[gc]);
        }
      }
  }
  __syncthreads();

  // ---- phase 3: d2 (K=256 -> 512 cols) -> sU2 ----
  {
    f32x4 a2[2][8];
#pragma unroll
    for (int i = 0; i < 2; ++i)
#pragma unroll
      for (int j = 0; j < 8; ++j) {
        f32x4 z = {0.f, 0.f, 0.f, 0.f};
        a2[i][j] = z;
      }
#pragma unroll
    for (int k0 = 0; k0 < 256; k0 += 32) {
      short8 af[2], bfr[8];
#pragma unroll
      for (int i = 0; i < 2; ++i)
        af[i] = *(const short8*)&sU1[(i * 16 + lrow) * 264 + k0 + quad * 8];
#pragma unroll
      for (int j = 0; j < 8; ++j)
        bfr[j] =
            *(const short8*)&Wd2[(wv * 128 + j * 16 + lrow) * 256 + k0 + quad * 8];
#pragma unroll
      for (int i = 0; i < 2; ++i)
#pragma unroll
        for (int j = 0; j < 8; ++j)
          a2[i][j] =
              __builtin_amdgcn_mfma_f32_16x16x32_bf16(af[i], bfr[j], a2[i][j], 0, 0, 0);
    }
#pragma unroll
    for (int i = 0; i < 2; ++i)
#pragma unroll
      for (int r = 0; r < 4; ++r) {
        int rl = i * 16 + quad * 4 + r;
#pragma unroll
        for (int j = 0; j < 8; ++j) {
          int gc = wv * 128 + j * 16 + lrow;
          sU2[rl * 520 + gc] = __float2bfloat16(a2[i][j][r] + db2[gc]);
        }
      }
  }
  __syncthreads();

  // ---- phase 4: d3 (K=512 -> 90 cols) -> out ----
  {
    f32x4 a3[2][2];
#pragma unroll
    for (int i = 0; i < 2; ++i)
#pragma unroll
      for (int j = 0; j < 2; ++j) {
        f32x4 z = {0.f, 0.f, 0.f, 0.f};
        a3[i][j] = z;
      }
#pragma unroll
    for (int k0 = 0; k0 < 512; k0 += 32) {
      short8 af[2], bfr[2];
#pragma unroll
      for (int i = 0; i < 2; ++i)
        af[i] = *(const short8*)&sU2[(i * 16 + lrow) * 520 + k0 + quad * 8];
#pragma unroll
      for (int j = 0; j < 2; ++j)
        bfr[j] =
            *(const short8*)&Wd3[(wv * 32 + j * 16 + lrow) * 512 + k0 + quad * 8];
#pragma unroll
      for (int i = 0; i < 2; ++i)
#pragma unroll
        for (int j = 0; j < 2; ++j)
          a3[i][j] =
              __builtin_amdgcn_mfma_f32_16x16x32_bf16(af[i], bfr[j], a3[i][j], 0, 0, 0);
    }
#pragma unroll
    for (int i = 0; i < 2; ++i)
#pragma unroll
      for (int r = 0; r < 4; ++r) {
        long gr = row0 + i * 16 + quad * 4 + r;
#pragma unroll
        for (int j = 0; j < 2; ++j) {
          int gc = wv * 32 + j * 16 + lrow;
          if (gc < 90) out[gr * 90 + gc] = a3[i][j][r] + db3[gc];
        }
      }
  }
}

// =============== k_tailq: proj+resid -> LN3 -> MLP(+gelu) -> resid [-> LN1' + QKV'] ===============
// 16-row blocks (grid 128).
template <bool QKV>
__global__ __launch_bounds__(256) void k_tailq(
    const bf16* __restrict__ obuf, float* __restrict__ jf, const bf16* __restrict__ Wp,
    const float* __restrict__ pb, const float* __restrict__ g3,
    const float* __restrict__ b3, const bf16* __restrict__ Wm1,
    const float* __restrict__ m1b, const bf16* __restrict__ Wm2,
    const float* __restrict__ m2b, const float* __restrict__ g1n,
    const float* __restrict__ b1n, const bf16* __restrict__ Wqn,
    const float* __restrict__ qbn, float* __restrict__ qkvb) {
  __shared__ __align__(16) bf16 sX[16 * XTS];
  __shared__ __align__(16) bf16 sH[16 * XTS];
  __shared__ float sstat[16][4][2];
  __shared__ float sstatF[16][2];

  const int t = threadIdx.x;
  const int lane = t & 63;
  const int wv = t >> 6;
  const int lrow = lane & 15, quad = lane >> 4;
  const long row0 = (long)blockIdx.x * 16;

  {
    int r = t >> 4, c8 = (t & 15) * 8;
    *(uint4*)&sX[r * XTS + c8] = *(const uint4*)&obuf[(row0 + r) * 128 + c8];
  }
  __syncthreads();

  // ---- proj GEMM (16x128, K=128), wave n-split 32 ----
  f32x4 acc[2];
  {
    f32x4 z = {0.f, 0.f, 0.f, 0.f};
    acc[0] = z;
    acc[1] = z;
  }
#pragma unroll
  for (int k0 = 0; k0 < 128; k0 += 32) {
    short8 af = *(const short8*)&sX[lrow * XTS + k0 + quad * 8];
    short8 bfr[2];
#pragma unroll
    for (int j = 0; j < 2; ++j)
      bfr[j] = *(const short8*)&Wp[(wv * 32 + j * 16 + lrow) * 128 + k0 + quad * 8];
#pragma unroll
    for (int j = 0; j < 2; ++j)
      acc[j] = __builtin_amdgcn_mfma_f32_16x16x32_bf16(af, bfr[j], acc[j], 0, 0, 0);
  }
#pragma unroll
  for (int r = 0; r < 4; ++r) {
    int rl = quad * 4 + r;
    long gr = row0 + rl;
    float s1 = 0.f, s2 = 0.f;
#pragma unroll
    for (int j = 0; j < 2; ++j) {
      int gc = wv * 32 + j * 16 + lrow;
      float v = acc[j][r] + pb[gc] + jf[gr * 128 + gc];
      acc[j][r] = v;
      jf[gr * 128 + gc] = v;
      s1 += v;
      s2 += v * v;
    }
#pragma unroll
    for (int m = 1; m < 16; m <<= 1) {
      s1 += __shfl_xor(s1, m, 64);
      s2 += __shfl_xor(s2, m, 64);
    }
    if (lrow == 0) {
      sstat[rl][wv][0] = s1;
      sstat[rl][wv][1] = s2;
    }
  }
  __syncthreads();
  if (t < 16) {
    float s1 = 0.f, s2 = 0.f;
#pragma unroll
    for (int w = 0; w < 4; ++w) {
      s1 += sstat[t][w][0];
      s2 += sstat[t][w][1];
    }
    float mu = s1 * (1.f / 128.f);
    float var = s2 * (1.f / 128.f) - mu * mu;
    sstatF[t][0] = mu;
    sstatF[t][1] = rsqrtf(var + 1e-5f);
  }
  __syncthreads();
#pragma unroll
  for (int r = 0; r < 4; ++r) {
    int rl = quad * 4 + r;
    float mu = sstatF[rl][0], inv = sstatF[rl][1];
#pragma unroll
    for (int j = 0; j < 2; ++j) {
      int gc = wv * 32 + j * 16 + lrow;
      sX[rl * XTS + gc] = __float2bfloat16((acc[j][r] - mu) * inv * g3[gc] + b3[gc]);
    }
  }
  __syncthreads();

  // ---- MLP1 + gelu ----
  f32x4 acc2[2];
  {
    f32x4 z = {0.f, 0.f, 0.f, 0.f};
    acc2[0] = z;
    acc2[1] = z;
  }
#pragma unroll
  for (int k0 = 0; k0 < 128; k0 += 32) {
    short8 af = *(const short8*)&sX[lrow * XTS + k0 + quad * 8];
    short8 bfr[2];
#pragma unroll
    for (int j = 0; j < 2; ++j)
      bfr[j] = *(const short8*)&Wm1[(wv * 32 + j * 16 + lrow) * 128 + k0 + quad * 8];
#pragma unroll
    for (int j = 0; j < 2; ++j)
      acc2[j] = __builtin_amdgcn_mfma_f32_16x16x32_bf16(af, bfr[j], acc2[j], 0, 0, 0);
  }
#pragma unroll
  for (int r = 0; r < 4; ++r) {
    int rl = quad * 4 + r;
#pragma unroll
    for (int j = 0; j < 2; ++j) {
      int gc = wv * 32 + j * 16 + lrow;
      float v = acc2[j][r] + m1b[gc];
      v = 0.5f * v * (1.f + erff(v * 0.70710678118654752f));
      sH[rl * XTS + gc] = __float2bfloat16(v);
    }
  }
  __syncthreads();

  // ---- MLP2 + resid [+ stats] ----
  f32x4 acc3[2];
  {
    f32x4 z = {0.f, 0.f, 0.f, 0.f};
    acc3[0] = z;
    acc3[1] = z;
  }
#pragma unroll
  for (int k0 = 0; k0 < 128; k0 += 32) {
    short8 af = *(const short8*)&sH[lrow * XTS + k0 + quad * 8];
    short8 bfr[2];
#pragma unroll
    for (int j = 0; j < 2; ++j)
      bfr[j] = *(const short8*)&Wm2[(wv * 32 + j * 16 + lrow) * 128 + k0 + quad * 8];
#pragma unroll
    for (int j = 0; j < 2; ++j)
      acc3[j] = __builtin_amdgcn_mfma_f32_16x16x32_bf16(af, bfr[j], acc3[j], 0, 0, 0);
  }
#pragma unroll
  for (int r = 0; r < 4; ++r) {
    int rl = quad * 4 + r;
    long gr = row0 + rl;
    float s1 = 0.f, s2 = 0.f;
#pragma unroll
    for (int j = 0; j < 2; ++j) {
      int gc = wv * 32 + j * 16 + lrow;
      float v = acc3[j][r] + m2b[gc] + jf[gr * 128 + gc];
      acc3[j][r] = v;
      jf[gr * 128 + gc] = v;
      if (QKV) {
        s1 += v;
        s2 += v * v;
      }
    }
    if (QKV) {
#pragma unroll
      for (int m = 1; m < 16; m <<= 1) {
        s1 += __shfl_xor(s1, m, 64);
        s2 += __shfl_xor(s2, m, 64);
      }
      if (lrow == 0) {
        sstat[rl][wv][0] = s1;
        sstat[rl][wv][1] = s2;
      }
    }
  }
  if (!QKV) return;
  __syncthreads();
  if (t < 16) {
    float s1 = 0.f, s2 = 0.f;
#pragma unroll
    for (int w = 0; w < 4; ++w) {
      s1 += sstat[t][w][0];
      s2 += sstat[t][w][1];
    }
    float mu = s1 * (1.f / 128.f);
    float var = s2 * (1.f / 128.f) - mu * mu;
    sstatF[t][0] = mu;
    sstatF[t][1] = rsqrtf(var + 1e-5f);
  }
  __syncthreads();
#pragma unroll
  for (int r = 0; r < 4; ++r) {
    int rl = quad * 4 + r;
    float mu = sstatF[rl][0], inv = sstatF[rl][1];
#pragma unroll
    for (int j = 0; j < 2; ++j) {
      int gc = wv * 32 + j * 16 + lrow;
      sX[rl * XTS + gc] = __float2bfloat16((acc3[j][r] - mu) * inv * g1n[gc] + b1n[gc]);
    }
  }
  __syncthreads();
  for (int p = 0; p < 3; ++p) {
    f32x4 acc4[2];
    {
      f32x4 z = {0.f, 0.f, 0.f, 0.f};
      acc4[0] = z;
      acc4[1] = z;
    }
#pragma unroll
    for (int k0 = 0; k0 < 128; k0 += 32) {
      short8 af = *(const short8*)&sX[lrow * XTS + k0 + quad * 8];
      short8 bfr[2];
#pragma unroll
      for (int j = 0; j < 2; ++j)
        bfr[j] = *(const short8*)&Wqn[(long)(p * 128 + wv * 32 + j * 16 + lrow) * 128 +
                                      k0 + quad * 8];
#pragma unroll
      for (int j = 0; j < 2; ++j)
        acc4[j] = __builtin_amdgcn_mfma_f32_16x16x32_bf16(af, bfr[j], acc4[j], 0, 0, 0);
    }
#pragma unroll
    for (int r = 0; r < 4; ++r) {
      long gr = row0 + quad * 4 + r;
#pragma unroll
      for (int j = 0; j < 2; ++j) {
        int gc = p * 128 + wv * 32 + j * 16 + lrow;
        qkvb[gr * 384 + gc] = acc4[j][r] + qbn[gc];
      }
    }
  }
}

// ---- prep (EARLY ONLY): weights needed by k_rel3 itself; late prep rides k_rel3 ----
__global__ void k_prep(const float* re_w1, const float* re_w2, const float* re_w3,
                       const float* ln2_g, const float* ln2_b, const float* rconv_w,
                       const float* rconv_b, const float* je_w1, const float* je_w2,
                       const float* je_w3, bf16* Wt1, bf16* Wt2, bf16* Wt3, bf16* gWt,
                       float* sgW, float* bconst, bf16* Wj1, bf16* Wj2, bf16* Wj3) {
  const int stride = gridDim.x * blockDim.x;
  const int tid = blockIdx.x * blockDim.x + threadIdx.x;
  for (int i = tid; i < 256 * 32; i += stride) {
    int n = i >> 5, k = i & 31;
    Wt1[i] = __float2bfloat16(k < 26 ? re_w1[k * 256 + n] : 0.f);
  }
  for (int i = tid; i < 256 * 256; i += stride) {
    int n = i >> 8, k = i & 255;
    Wt2[i] = __float2bfloat16(re_w2[k * 256 + n]);
  }
  for (int i = tid; i < 128 * 256; i += stride) {
    int n = i >> 8, k = i & 255;
    Wt3[i] = __float2bfloat16(re_w3[k * 128 + n]);
  }
  for (int i = tid; i < 32 * 128; i += stride) {
    int col = i >> 7, c = i & 127;
    int dd = col >> 3, h = col & 7;
    gWt[i] = __float2bfloat16(ln2_g[dd * 128 + c] * rconv_w[(dd * 128 + c) * 8 + h]);
  }
  if (tid < 32) {
    int dd = tid >> 3, h = tid & 7;
    float sg = 0.f, bc = 0.f;
    for (int c = 0; c < 128; ++c) {
      float w = rconv_w[(dd * 128 + c) * 8 + h];
      sg += ln2_g[dd * 128 + c] * w;
      bc += ln2_b[dd * 128 + c] * w;
    }
    sgW[tid] = sg;
    bconst[tid] = bc + rconv_b[tid];
  }
  for (int i = tid; i < 256 * 96; i += stride) {
    int n = i / 96, k = i - n * 96;
    Wj1[i] = __float2bfloat16(je_w1[k * 256 + n]);
  }
  for (int i = tid; i < 256 * 256; i += stride) {
    int n = i >> 8, k = i & 255;
    Wj2[i] = __float2bfloat16(je_w2[k * 256 + n]);
  }
  for (int i = tid; i < 128 * 256; i += stride) {
    int n = i >> 8, k = i & 255;
    Wj3[i] = __float2bfloat16(je_w3[k * 128 + n]);
  }
}

// ---- fused attention: 4 independent waves per block, one wave per (b,h,n) ----
__global__ __launch_bounds__(256) void k_attn(const float* __restrict__ qkv,
                                              const bf16* __restrict__ aR,
                                              const float* __restrict__ conn,
                                              bf16* __restrict__ obuf) {
  __shared__ float p[4][4 * 68];
  const int wv = threadIdx.x >> 6;
  const int n = blockIdx.x * 4 + wv;
  const int h = blockIdx.y, b = blockIdx.z;
  const int lane = threadIdx.x & 63;
  const long rowq = (long)(b * Nn + n);
  const float* qp = &qkv[rowq * 384 + h * 16];
  f32x4 q0 = *(const f32x4*)qp;
  f32x4 q1 = *(const f32x4*)(qp + 4);
  f32x4 q2 = *(const f32x4*)(qp + 8);
  f32x4 q3 = *(const f32x4*)(qp + 12);
  const bf16* arp = &aR[((long)(b * Hh + h) * Nn + n) * Nn];
  const float* cnp = &conn[rowq * Nn];

  float lg[4];
#pragma unroll
  for (int s = 0; s < 4; ++s) {
    int m = s * 64 + lane;
    const float* kp = &qkv[((long)(b * Nn + m)) * 384 + 128 + h * 16];
    f32x4 k0 = *(const f32x4*)kp;
    f32x4 k1 = *(const f32x4*)(kp + 4);
    f32x4 k2 = *(const f32x4*)(kp + 8);
    f32x4 k3 = *(const f32x4*)(kp + 12);
    float d = 0.f;
#pragma unroll
    for (int e = 0; e < 4; ++e)
      d += q0[e] * k0[e] + q1[e] * k1[e] + q2[e] * k2[e] + q3[e] * k3[e];
    d += __bfloat162float(arp[m]);
    lg[s] = d * cnp[m] * 0.25f;
  }
  float mx = fmaxf(fmaxf(lg[0], lg[1]), fmaxf(lg[2], lg[3]));
#pragma unroll
  for (int off = 32; off; off >>= 1) mx = fmaxf(mx, __shfl_xor(mx, off, 64));
  float ex[4], ssum = 0.f;
#pragma unroll
  for (int s = 0; s < 4; ++s) {
    ex[s] = expf(lg[s] - mx);
    ssum += ex[s];
  }
#pragma unroll
  for (int off = 32; off; off >>= 1) ssum += __shfl_xor(ssum, off, 64);
#pragma unroll
  for (int s = 0; s < 4; ++s) p[wv][s * 68 + lane] = ex[s];
  float rinv = 1.f / ssum;

  const int c = lane & 15, sg = lane >> 4;
  const float* vp = &qkv[((long)(b * Nn + sg * 64)) * 384 + 256 + h * 16 + c];
  float acc = 0.f;
#pragma unroll
  for (int u = 0; u < 16; ++u) {
    f32x4 pq = *(const f32x4*)&p[wv][sg * 68 + u * 4];
#pragma unroll
    for (int e = 0; e < 4; ++e) acc += pq[e] * vp[(long)(u * 4 + e) * 384];
  }
  acc += __shfl_xor(acc, 16, 64);
  acc += __shfl_xor(acc, 32, 64);
  if (lane < 16) obuf[rowq * 128 + h * 16 + lane] = __float2bfloat16(acc * rinv);
}

extern "C" void kernel_launch(void* const* d_in, const int* in_sizes, int n_in,
                              void* d_out, int out_size, void* d_ws, size_t ws_size,
                              hipStream_t stream) {
  const float* joint_in = (const float*)d_in[0];
  const float* relation_in = (const float*)d_in[1];
  const float* conn = (const float*)d_in[2];
  const float* je_w1 = (const float*)d_in[3];
  const float* je_b1 = (const float*)d_in[4];
  const float* je_w2 = (const float*)d_in[5];
  const float* je_b2 = (const float*)d_in[6];
  const float* je_w3 = (const float*)d_in[7];
  const float* je_b3 = (const float*)d_in[8];
  const float* re_w1 = (const float*)d_in[9];
  const float* re_b1 = (const float*)d_in[10];
  const float* re_w2 = (const float*)d_in[11];
  const float* re_b2 = (const float*)d_in[12];
  const float* re_w3 = (const float*)d_in[13];
  const float* re_b3 = (const float*)d_in[14];
  const float* qkv_w = (const float*)d_in[15];
  const float* qkv_b = (const float*)d_in[16];
  const float* rconv_w = (const float*)d_in[17];
  const float* rconv_b = (const float*)d_in[18];
  const float* proj_w = (const float*)d_in[19];
  const float* proj_b = (const float*)d_in[20];
  const float* ln1_g = (const float*)d_in[21];
  const float* ln1_b = (const float*)d_in[22];
  const float* ln2_g = (const float*)d_in[23];
  const float* ln2_b = (const float*)d_in[24];
  const float* ln3_g = (const float*)d_in[25];
  const float* ln3_b = (const float*)d_in[26];
  const float* mw1 = (const float*)d_in[27];
  const float* mb1 = (const float*)d_in[28];
  const float* mw2 = (const float*)d_in[29];
  const float* mb2 = (const float*)d_in[30];
  const float* ng = (const float*)d_in[31];
  const float* nb = (const float*)d_in[32];
  const float* dw1 = (const float*)d_in[33];
  const float* db1 = (const float*)d_in[34];
  const float* dw2 = (const float*)d_in[35];
  const float* db2 = (const float*)d_in[36];
  const float* dw3 = (const float*)d_in[37];
  const float* db3 = (const float*)d_in[38];

  char* ws = (char*)d_ws;
  size_t off = 0;
  auto alloc = [&](size_t bytes) -> void* {
    void* p = ws + off;
    off += (bytes + 255) & ~(size_t)255;
    return p;
  };
  bf16* attnR = (bf16*)alloc((size_t)DEPTHd * Bb * Hh * Nn * Nn * 2);
  bf16* Wt1 = (bf16*)alloc(256 * 32 * 2);
  bf16* Wt2 = (bf16*)alloc(256 * 256 * 2);
  bf16* Wt3 = (bf16*)alloc(128 * 256 * 2);
  bf16* gWt = (bf16*)alloc(32 * 128 * 2);
  float* sgW = (float*)alloc(32 * 4);
  float* bconst = (float*)alloc(32 * 4);
  bf16* Wj1 = (bf16*)alloc(256 * 96 * 2);
  bf16* Wj2 = (bf16*)alloc(256 * 256 * 2);
  bf16* Wj3 = (bf16*)alloc(128 * 256 * 2);
  bf16* Wq = (bf16*)alloc(4 * 384 * 128 * 2);
  bf16* Wp = (bf16*)alloc(4 * 128 * 128 * 2);
  bf16* Wm1 = (bf16*)alloc(4 * 128 * 128 * 2);
  bf16* Wm2 = (bf16*)alloc(4 * 128 * 128 * 2);
  bf16* Wd1 = (bf16*)alloc(256 * 128 * 2);
  bf16* Wd2 = (bf16*)alloc(512 * 256 * 2);
  bf16* Wd3 = (bf16*)alloc(128 * 512 * 2);
  float* jf = (float*)alloc((size_t)BN * 128 * 4);
  bf16* obuf = (bf16*)alloc((size_t)BN * 128 * 2);
  char* U = (char*)alloc((size_t)BN * 384 * 4);
  float* qkvb = (float*)U;

  // early prep: only what k_rel3 consumes (Wt*, Wj*, gWt, sgW, bconst)
  k_prep<<<dim3(256), dim3(256), 0, stream>>>(
      re_w1, re_w2, re_w3, ln2_g, ln2_b, rconv_w, rconv_b, je_w1, je_w2, je_w3,
      Wt1, Wt2, Wt3, gWt, sgW, bconst, Wj1, Wj2, Wj3);

  // relation encoder (fills attnR) + joint encoder (fills jf) + late weight prep
  k_rel3<<<dim3(RELB + JB + PREPB), dim3(256), 0, stream>>>(
      relation_in, Wt1, re_b1, Wt2, re_b2, Wt3, re_b3, gWt, sgW, bconst, attnR,
      joint_in, Wj1, je_b1, Wj2, je_b2, Wj3, je_b3, jf,
      qkv_w, proj_w, mw1, mw2, dw1, dw2, dw3, Wq, Wp, Wm1, Wm2, Wd1, Wd2, Wd3);

  // depth 0 QKV
  k_lnqkv<float><<<dim3(3, 64), dim3(256), 0, stream>>>(
      jf, ln1_g, ln1_b, Wq, qkv_b, qkvb, 384, 384);

  for (int d = 0; d < DEPTHd; ++d) {
    k_attn<<<dim3(Nn / 4, Hh, Bb), dim3(256), 0, stream>>>(
        qkvb, attnR + (size_t)d * Bb * Hh * Nn * Nn, conn, obuf);
    if (d < 3) {
      k_tailq<true><<<dim3(128), dim3(256), 0, stream>>>(
          obuf, jf, Wp + (size_t)d * 16384, proj_b + d * 128, ln3_g + d * 128,
          ln3_b + d * 128, Wm1 + (size_t)d * 16384, mb1 + d * 128,
          Wm2 + (size_t)d * 16384, mb2 + d * 128, ln1_g + (d + 1) * 128,
          ln1_b + (d + 1) * 128, Wq + (size_t)(d + 1) * 49152, qkv_b + (d + 1) * 384,
          qkvb);
    } else {
      k_tailq<false><<<dim3(128), dim3(256), 0, stream>>>(
          obuf, jf, Wp + (size_t)d * 16384, proj_b + d * 128, ln3_g + d * 128,
          ln3_b + d * 128, Wm1 + (size_t)d * 16384, mb1 + d * 128,
          Wm2 + (size_t)d * 16384, mb2 + d * 128, nullptr, nullptr, nullptr, nullptr,
          nullptr);
    }
  }

  // fused final LN + decoder (256 -> 512 -> 90)
  k_dec<<<dim3(64), dim3(256), 0, stream>>>(jf, ng, nb, Wd1, db1, Wd2, db2, Wd3, db3,
                                            (float*)d_out);
}

// Round 11
// 613.466 us; speedup vs baseline: 1.1309x; 1.0477x over previous
//
#include <hip/hip_runtime.h>
#include <hip/hip_bf16.h>
#include <math.h>

typedef __hip_bfloat16 bf16;
typedef __attribute__((ext_vector_type(8))) short short8;
typedef __attribute__((ext_vector_type(4))) short s16x4;
typedef __attribute__((ext_vector_type(4))) float f32x4;
typedef __attribute__((ext_vector_type(2))) float f32x2;

#define Bb 8
#define Nn 256
#define Hh 8
#define DEPTHd 4
#define BN 2048
#define RTOT 524288
#define RELB 8192          // RTOT/64 relation blocks
#define JB 32              // BN/64 joint blocks
#define XTS 136
#define X3S 136

__device__ inline float toF(float v) { return v; }
__device__ inline float toF(bf16 v) { return __bfloat162float(v); }
__device__ inline void stF(float* p, float v) { *p = v; }
__device__ inline void stF(bf16* p, float v) { *p = __float2bfloat16(v); }

// =============== k_relF: FOLDED relation + joint encoders ===============
// KEY INSIGHT (round 11): _mlp_stack has IDENTITY activation -> the 3-layer
// encoders are pure linear chains. W123 = re_w1@re_w2@re_w3 (26x128) folds
// offline (k_prep0/1), so the rel path is ONE K=32 GEMM (8 MFMA/wave, W123t
// L2-hot direct-global) + the PROVEN LN-stats + gemm32 epilogue, instead of
// the 237us L1/L2/L3 staged pipeline. Joint: Wj123 (96x128), one K=96 GEMM.
// FLOP drops 33x; kernel becomes memory-ish bound (54MB rin + 34MB attnR).
// Blocks [0,RELB): relation -> attnR. [RELB,RELB+JB): joint -> jf.
__global__ __launch_bounds__(256) void k_relF(
    const float* __restrict__ rin, const bf16* __restrict__ W123t,
    const float* __restrict__ b123, const bf16* __restrict__ gWt,
    const float* __restrict__ sgW, const float* __restrict__ bconst,
    bf16* __restrict__ attnR, const float* __restrict__ jin,
    const bf16* __restrict__ Wj123t, const float* __restrict__ bj123,
    float* __restrict__ jf) {
  __shared__ __align__(16) char smem[17920];
  bf16* x3 = (bf16*)smem;               // [64][136] = 17408
  float* sstatF = (float*)(smem + 17408);  // [64][2] = 512

  const int t = threadIdx.x;
  const int lane = t & 63, wv = t >> 6;
  const int lrow = lane & 15, quad = lane >> 4;
  const bool rel = blockIdx.x < RELB;

  if (!rel) {
    // ---- joint: jf = jin @ Wj123 + bj123 (K=96, 128 cols) ----
    const long r0j = (long)(blockIdx.x - RELB) * 64;
    const long gj = r0j + wv * 16 + lrow;
    short8 aj[3];
#pragma unroll
    for (int ks = 0; ks < 3; ++ks) {
      const float* ap = &jin[gj * 96 + ks * 32 + quad * 8];
      f32x4 f0 = *(const f32x4*)ap;
      f32x4 f1 = *(const f32x4*)(ap + 4);
      bf16 pk[8];
#pragma unroll
      for (int u = 0; u < 4; ++u) {
        pk[u] = __float2bfloat16(f0[u]);
        pk[u + 4] = __float2bfloat16(f1[u]);
      }
      aj[ks] = *(short8*)pk;
    }
#pragma unroll
    for (int cb = 0; cb < 4; ++cb)
#pragma unroll
      for (int ct = 0; ct < 2; ++ct) {
        int colb = cb * 32 + ct * 16;
        f32x4 x = {0.f, 0.f, 0.f, 0.f};
#pragma unroll
        for (int ks = 0; ks < 3; ++ks) {
          short8 bw = *(const short8*)&Wj123t[(colb + lrow) * 96 + ks * 32 + quad * 8];
          x = __builtin_amdgcn_mfma_f32_16x16x32_bf16(bw, aj[ks], x, 0, 0, 0);
        }
        f32x4 bq = *(const f32x4*)&bj123[colb + quad * 4];
        f32x4 out;
#pragma unroll
        for (int r = 0; r < 4; ++r) out[r] = x[r] + bq[r];
        *(f32x4*)&jf[gj * 128 + colb + quad * 4] = out;
      }
    return;
  }

  // ---- rel: y = rin @ W123 + b123 (K=32, 128 cols) -> LN-fold 1x1conv ----
  // A-frag: per-lane 8 k-elements of row wv*16+lrow (26 valid, zero-padded)
  short8 a0;
  {
    const long gr = (long)blockIdx.x * 64 + wv * 16 + lrow;
    const float* ap = &rin[gr * 26];
    float v[8];
    if (quad < 3) {
#pragma unroll
      for (int u = 0; u < 4; ++u) {
        f32x2 f = *(const f32x2*)(ap + quad * 8 + u * 2);
        v[u * 2] = f[0];
        v[u * 2 + 1] = f[1];
      }
    } else {
      f32x2 f = *(const f32x2*)(ap + 24);
      v[0] = f[0];
      v[1] = f[1];
#pragma unroll
      for (int u = 2; u < 8; ++u) v[u] = 0.f;
    }
    bf16 pk[8];
#pragma unroll
    for (int u = 0; u < 8; ++u) pk[u] = __float2bfloat16(v[u]);
    a0 = *(short8*)pk;
  }

  // production: lane -> row wv*16+lrow, cols colb+quad*4..+3; per-lane LN partials
  float s1 = 0.f, s2 = 0.f;
#pragma unroll
  for (int cb = 0; cb < 4; ++cb)
#pragma unroll
    for (int ct = 0; ct < 2; ++ct) {
      int colb = cb * 32 + ct * 16;
      f32x4 x = {0.f, 0.f, 0.f, 0.f};
      short8 bw = *(const short8*)&W123t[(colb + lrow) * 32 + quad * 8];
      x = __builtin_amdgcn_mfma_f32_16x16x32_bf16(bw, a0, x, 0, 0, 0);
      f32x4 bq = *(const f32x4*)&b123[colb + quad * 4];
      bf16 pk[4];
#pragma unroll
      for (int r = 0; r < 4; ++r) {
        float v = x[r] + bq[r];
        pk[r] = __float2bfloat16(v);
        s1 += v;
        s2 += v * v;
      }
      *(s16x4*)&x3[(wv * 16 + lrow) * X3S + colb + quad * 4] = *(s16x4*)pk;
    }
  // quad-reduce -> full row stats (lanes ^16,^32 share lrow)
  s1 += __shfl_xor(s1, 16, 64);
  s2 += __shfl_xor(s2, 16, 64);
  s1 += __shfl_xor(s1, 32, 64);
  s2 += __shfl_xor(s2, 32, 64);
  if (quad == 0) {
    int row = wv * 16 + lrow;
    float mu = s1 * (1.f / 128.f);
    float var = s2 * (1.f / 128.f) - mu * mu;
    sstatF[row * 2] = mu;
    sstatF[row * 2 + 1] = rsqrtf(var + 1e-5f);
  }
  // hoist gemm32 A-operands (gWt, L1/L2-hot)
  short8 aw0[4], aw1[4];
#pragma unroll
  for (int kk = 0; kk < 4; ++kk) {
    aw0[kk] = *(const short8*)&gWt[lrow * 128 + kk * 32 + quad * 8];
    aw1[kk] = *(const short8*)&gWt[(16 + lrow) * 128 + kk * 32 + quad * 8];
  }
  __syncthreads();

  // ---- gemm32: 32 out-chans x 64 rows (wave = 16 rows), LN stats trick, scatter ----
  {
    f32x4 ac0 = {0.f, 0.f, 0.f, 0.f}, ac1 = {0.f, 0.f, 0.f, 0.f};
#pragma unroll
    for (int kk = 0; kk < 4; ++kk) {
      short8 bbx = *(const short8*)&x3[(wv * 16 + lrow) * X3S + kk * 32 + quad * 8];
      ac0 = __builtin_amdgcn_mfma_f32_16x16x32_bf16(aw0[kk], bbx, ac0, 0, 0, 0);
      ac1 = __builtin_amdgcn_mfma_f32_16x16x32_bf16(aw1[kk], bbx, ac1, 0, 0, 0);
    }
    const long r0 = (long)blockIdx.x * 64;
    int drow = wv * 16 + lrow;
    long gr = r0 + drow;
    float mu = sstatF[drow * 2], inv = sstatF[drow * 2 + 1];
    int bb_ = (int)(gr >> 16);
    int nn = (int)((gr >> 8) & 255);
    int mm = (int)(gr & 255);
#pragma unroll
    for (int mt = 0; mt < 2; ++mt) {
      f32x4 a = mt ? ac1 : ac0;
#pragma unroll
      for (int reg = 0; reg < 4; ++reg) {
        int col = mt * 16 + quad * 4 + reg;
        float v = inv * (a[reg] - mu * sgW[col]) + bconst[col];
        int dd = col >> 3, hh = col & 7;
        attnR[((((long)dd * Bb + bb_) * Hh + hh) * Nn + nn) * Nn + mm] =
            __float2bfloat16(v);
      }
    }
  }
}

// =============== k_prep0: stage-A folds + gW fold + per-depth transposes ===============
// F = re_w1@re_w2 (26x256), bT = re_b1@re_w2+re_b2, Fj = je_w1@je_w2 (96x256),
// bTj, G = dw2@dw3 (256x90), u1 = db1@dw2 (512), gWt/sgW/bconst, Wq/Wp/Wm1/Wm2.
__global__ void k_prep0(const float* re_w1, const float* re_w2, const float* re_b1,
                        const float* re_b2, const float* je_w1, const float* je_w2,
                        const float* je_b1, const float* je_b2, const float* dw2,
                        const float* dw3, const float* db1, const float* ln2_g,
                        const float* ln2_b, const float* rconv_w, const float* rconv_b,
                        const float* qkv_w, const float* proj_w, const float* mw1,
                        const float* mw2, float* F, float* bT, float* Fj, float* bTj,
                        float* G, float* u1, bf16* gWt, float* sgW, float* bconst,
                        bf16* Wq, bf16* Wp, bf16* Wm1, bf16* Wm2) {
  const int stride = gridDim.x * blockDim.x;
  const int tid = blockIdx.x * blockDim.x + threadIdx.x;
  for (int i = tid; i < 26 * 256; i += stride) {
    int k = i >> 8, d = i & 255;
    float v = 0.f;
    for (int c = 0; c < 256; ++c) v += re_w1[k * 256 + c] * re_w2[c * 256 + d];
    F[i] = v;
  }
  for (int i = tid; i < 256; i += stride) {
    float v = 0.f;
    for (int c = 0; c < 256; ++c) v += re_b1[c] * re_w2[c * 256 + i];
    bT[i] = v + re_b2[i];
  }
  for (int i = tid; i < 96 * 256; i += stride) {
    int k = i >> 8, d = i & 255;
    float v = 0.f;
    for (int c = 0; c < 256; ++c) v += je_w1[k * 256 + c] * je_w2[c * 256 + d];
    Fj[i] = v;
  }
  for (int i = tid; i < 256; i += stride) {
    float v = 0.f;
    for (int c = 0; c < 256; ++c) v += je_b1[c] * je_w2[c * 256 + i];
    bTj[i] = v + je_b2[i];
  }
  for (int i = tid; i < 256 * 90; i += stride) {
    int c = i / 90, m = i - c * 90;
    float v = 0.f;
    for (int d = 0; d < 512; ++d) v += dw2[c * 512 + d] * dw3[d * 90 + m];
    G[i] = v;
  }
  for (int i = tid; i < 512; i += stride) {
    float v = 0.f;
    for (int c = 0; c < 256; ++c) v += db1[c] * dw2[c * 512 + i];
    u1[i] = v;
  }
  for (int i = tid; i < 32 * 128; i += stride) {
    int col = i >> 7, c = i & 127;
    int dd = col >> 3, h = col & 7;
    gWt[i] = __float2bfloat16(ln2_g[dd * 128 + c] * rconv_w[(dd * 128 + c) * 8 + h]);
  }
  if (tid < 32) {
    int dd = tid >> 3, h = tid & 7;
    float sg = 0.f, bc = 0.f;
    for (int c = 0; c < 128; ++c) {
      float w = rconv_w[(dd * 128 + c) * 8 + h];
      sg += ln2_g[dd * 128 + c] * w;
      bc += ln2_b[dd * 128 + c] * w;
    }
    sgW[tid] = sg;
    bconst[tid] = bc + rconv_b[tid];
  }
  for (int i = tid; i < 4 * 384 * 128; i += stride) {
    int d = i / 49152, rem = i - d * 49152;
    int n = rem >> 7, k = rem & 127;
    Wq[i] = __float2bfloat16(qkv_w[d * 49152 + k * 384 + n]);
  }
  for (int i = tid; i < 4 * 128 * 128; i += stride) {
    int d = i >> 14, rem = i & 16383;
    int n = rem >> 7, k = rem & 127;
    Wp[i] = __float2bfloat16(proj_w[d * 16384 + k * 128 + n]);
    Wm1[i] = __float2bfloat16(mw1[d * 16384 + k * 128 + n]);
    Wm2[i] = __float2bfloat16(mw2[d * 16384 + k * 128 + n]);
  }
}

// =============== k_prep1: stage-B folds (need stage-A outputs) ===============
// W123t [128 cols][32 k] bf16 (k>=26 zero), b123; Wj123t [128][96]; bj123;
// Wd123t [128 cols][128 k] (cols>=90 zero), bd123p (padded 128).
__global__ void k_prep1(const float* F, const float* bT, const float* re_w3,
                        const float* re_b3, const float* Fj, const float* bTj,
                        const float* je_w3, const float* je_b3, const float* dw1,
                        const float* G, const float* u1, const float* db2,
                        const float* dw3, const float* db3, bf16* W123t, float* b123,
                        bf16* Wj123t, float* bj123, bf16* Wd123t, float* bd123p) {
  const int stride = gridDim.x * blockDim.x;
  const int tid = blockIdx.x * blockDim.x + threadIdx.x;
  for (int i = tid; i < 128 * 32; i += stride) {
    int m = i >> 5, k = i & 31;
    float v = 0.f;
    if (k < 26)
      for (int d = 0; d < 256; ++d) v += F[k * 256 + d] * re_w3[d * 128 + m];
    W123t[i] = __float2bfloat16(v);
  }
  for (int i = tid; i < 128; i += stride) {
    float v = 0.f;
    for (int d = 0; d < 256; ++d) v += bT[d] * re_w3[d * 128 + i];
    b123[i] = v + re_b3[i];
  }
  for (int i = tid; i < 128 * 96; i += stride) {
    int m = i / 96, k = i - m * 96;
    float v = 0.f;
    for (int d = 0; d < 256; ++d) v += Fj[k * 256 + d] * je_w3[d * 128 + m];
    Wj123t[i] = __float2bfloat16(v);
  }
  for (int i = tid; i < 128; i += stride) {
    float v = 0.f;
    for (int d = 0; d < 256; ++d) v += bTj[d] * je_w3[d * 128 + i];
    bj123[i] = v + je_b3[i];
  }
  for (int i = tid; i < 128 * 128; i += stride) {
    int m = i >> 7, k = i & 127;
    float v = 0.f;
    if (m < 90)
      for (int c = 0; c < 256; ++c) v += dw1[k * 256 + c] * G[c * 90 + m];
    Wd123t[i] = __float2bfloat16(v);
  }
  for (int i = tid; i < 128; i += stride) {
    float v = 0.f;
    if (i < 90) {
      for (int d = 0; d < 512; ++d) v += (u1[d] + db2[d]) * dw3[d * 90 + i];
      v += db3[i];
    }
    bd123p[i] = v;
  }
}

// =============== k_lnqkv: row-LN (dim 128) fused into K=128 GEMM, 32-row blocks ===============
// Used for depth-0 QKV (ncols=384) AND the folded decoder (Wd123t, ncols=90).
template <typename TC>
__global__ __launch_bounds__(256) void k_lnqkv(
    const float* __restrict__ A, const float* __restrict__ g,
    const float* __restrict__ b, const bf16* __restrict__ Bt,
    const float* __restrict__ bias, TC* __restrict__ C, int ldc, int ncols) {
  __shared__ __align__(16) bf16 sX[32 * XTS];
  const int t = threadIdx.x;
  const int lane = t & 63;
  const int wv = t >> 6;
  const int lrow = lane & 15, quad = lane >> 4;
  const long row0 = (long)blockIdx.y * 32;
  const int n0 = blockIdx.x * 128;

  {
    int row = t >> 3, prt = t & 7;
    const float* ap = &A[(row0 + row) * 128 + prt * 16];
    float v[16];
    float s1 = 0.f, s2 = 0.f;
#pragma unroll
    for (int u = 0; u < 4; ++u) {
      f32x4 q = *(const f32x4*)(ap + u * 4);
#pragma unroll
      for (int e = 0; e < 4; ++e) {
        v[u * 4 + e] = q[e];
        s1 += q[e];
        s2 += q[e] * q[e];
      }
    }
    s1 += __shfl_xor(s1, 1, 64);
    s2 += __shfl_xor(s2, 1, 64);
    s1 += __shfl_xor(s1, 2, 64);
    s2 += __shfl_xor(s2, 2, 64);
    s1 += __shfl_xor(s1, 4, 64);
    s2 += __shfl_xor(s2, 4, 64);
    float mu = s1 * (1.f / 128.f);
    float inv = rsqrtf(s2 * (1.f / 128.f) - mu * mu + 1e-5f);
#pragma unroll
    for (int u4 = 0; u4 < 4; ++u4) {
      bf16 pk[4];
#pragma unroll
      for (int e = 0; e < 4; ++e) {
        int c = prt * 16 + u4 * 4 + e;
        pk[e] = __float2bfloat16((v[u4 * 4 + e] - mu) * inv * g[c] + b[c]);
      }
      *(s16x4*)&sX[row * XTS + prt * 16 + u4 * 4] = *(s16x4*)pk;
    }
  }
  __syncthreads();

  f32x4 acc[2][2];
#pragma unroll
  for (int i = 0; i < 2; ++i)
#pragma unroll
    for (int j = 0; j < 2; ++j) {
      f32x4 z = {0.f, 0.f, 0.f, 0.f};
      acc[i][j] = z;
    }
#pragma unroll
  for (int k0 = 0; k0 < 128; k0 += 32) {
    short8 af[2], bfr[2];
#pragma unroll
    for (int j = 0; j < 2; ++j)
      bfr[j] = *(const short8*)&Bt[(long)(n0 + wv * 32 + j * 16 + lrow) * 128 + k0 +
                                   quad * 8];
#pragma unroll
    for (int i = 0; i < 2; ++i)
      af[i] = *(const short8*)&sX[(i * 16 + lrow) * XTS + k0 + quad * 8];
#pragma unroll
    for (int i = 0; i < 2; ++i)
#pragma unroll
      for (int j = 0; j < 2; ++j)
        acc[i][j] =
            __builtin_amdgcn_mfma_f32_16x16x32_bf16(af[i], bfr[j], acc[i][j], 0, 0, 0);
  }
#pragma unroll
  for (int i = 0; i < 2; ++i) {
#pragma unroll
    for (int r = 0; r < 4; ++r) {
      long gr = row0 + i * 16 + quad * 4 + r;
#pragma unroll
      for (int j = 0; j < 2; ++j) {
        int gc = n0 + wv * 32 + j * 16 + lrow;
        if (gc < ncols) stF(&C[gr * (long)ldc + gc], acc[i][j][r] + bias[gc]);
      }
    }
  }
}

// =============== k_tailq: proj+resid -> LN3 -> MLP(+gelu) -> resid [-> LN1' + QKV'] ===============
// 16-row blocks (grid 128).
template <bool QKV>
__global__ __launch_bounds__(256) void k_tailq(
    const bf16* __restrict__ obuf, float* __restrict__ jf, const bf16* __restrict__ Wp,
    const float* __restrict__ pb, const float* __restrict__ g3,
    const float* __restrict__ b3, const bf16* __restrict__ Wm1,
    const float* __restrict__ m1b, const bf16* __restrict__ Wm2,
    const float* __restrict__ m2b, const float* __restrict__ g1n,
    const float* __restrict__ b1n, const bf16* __restrict__ Wqn,
    const float* __restrict__ qbn, float* __restrict__ qkvb) {
  __shared__ __align__(16) bf16 sX[16 * XTS];
  __shared__ __align__(16) bf16 sH[16 * XTS];
  __shared__ float sstat[16][4][2];
  __shared__ float sstatF[16][2];

  const int t = threadIdx.x;
  const int lane = t & 63;
  const int wv = t >> 6;
  const int lrow = lane & 15, quad = lane >> 4;
  const long row0 = (long)blockIdx.x * 16;

  {
    int r = t >> 4, c8 = (t & 15) * 8;
    *(uint4*)&sX[r * XTS + c8] = *(const uint4*)&obuf[(row0 + r) * 128 + c8];
  }
  __syncthreads();

  // ---- proj GEMM (16x128, K=128), wave n-split 32 ----
  f32x4 acc[2];
  {
    f32x4 z = {0.f, 0.f, 0.f, 0.f};
    acc[0] = z;
    acc[1] = z;
  }
#pragma unroll
  for (int k0 = 0; k0 < 128; k0 += 32) {
    short8 af = *(const short8*)&sX[lrow * XTS + k0 + quad * 8];
    short8 bfr[2];
#pragma unroll
    for (int j = 0; j < 2; ++j)
      bfr[j] = *(const short8*)&Wp[(wv * 32 + j * 16 + lrow) * 128 + k0 + quad * 8];
#pragma unroll
    for (int j = 0; j < 2; ++j)
      acc[j] = __builtin_amdgcn_mfma_f32_16x16x32_bf16(af, bfr[j], acc[j], 0, 0, 0);
  }
#pragma unroll
  for (int r = 0; r < 4; ++r) {
    int rl = quad * 4 + r;
    long gr = row0 + rl;
    float s1 = 0.f, s2 = 0.f;
#pragma unroll
    for (int j = 0; j < 2; ++j) {
      int gc = wv * 32 + j * 16 + lrow;
      float v = acc[j][r] + pb[gc] + jf[gr * 128 + gc];
      acc[j][r] = v;
      jf[gr * 128 + gc] = v;
      s1 += v;
      s2 += v * v;
    }
#pragma unroll
    for (int m = 1; m < 16; m <<= 1) {
      s1 += __shfl_xor(s1, m, 64);
      s2 += __shfl_xor(s2, m, 64);
    }
    if (lrow == 0) {
      sstat[rl][wv][0] = s1;
      sstat[rl][wv][1] = s2;
    }
  }
  __syncthreads();
  if (t < 16) {
    float s1 = 0.f, s2 = 0.f;
#pragma unroll
    for (int w = 0; w < 4; ++w) {
      s1 += sstat[t][w][0];
      s2 += sstat[t][w][1];
    }
    float mu = s1 * (1.f / 128.f);
    float var = s2 * (1.f / 128.f) - mu * mu;
    sstatF[t][0] = mu;
    sstatF[t][1] = rsqrtf(var + 1e-5f);
  }
  __syncthreads();
#pragma unroll
  for (int r = 0; r < 4; ++r) {
    int rl = quad * 4 + r;
    float mu = sstatF[rl][0], inv = sstatF[rl][1];
#pragma unroll
    for (int j = 0; j < 2; ++j) {
      int gc = wv * 32 + j * 16 + lrow;
      sX[rl * XTS + gc] = __float2bfloat16((acc[j][r] - mu) * inv * g3[gc] + b3[gc]);
    }
  }
  __syncthreads();

  // ---- MLP1 + gelu ----
  f32x4 acc2[2];
  {
    f32x4 z = {0.f, 0.f, 0.f, 0.f};
    acc2[0] = z;
    acc2[1] = z;
  }
#pragma unroll
  for (int k0 = 0; k0 < 128; k0 += 32) {
    short8 af = *(const short8*)&sX[lrow * XTS + k0 + quad * 8];
    short8 bfr[2];
#pragma unroll
    for (int j = 0; j < 2; ++j)
      bfr[j] = *(const short8*)&Wm1[(wv * 32 + j * 16 + lrow) * 128 + k0 + quad * 8];
#pragma unroll
    for (int j = 0; j < 2; ++j)
      acc2[j] = __builtin_amdgcn_mfma_f32_16x16x32_bf16(af, bfr[j], acc2[j], 0, 0, 0);
  }
#pragma unroll
  for (int r = 0; r < 4; ++r) {
    int rl = quad * 4 + r;
#pragma unroll
    for (int j = 0; j < 2; ++j) {
      int gc = wv * 32 + j * 16 + lrow;
      float v = acc2[j][r] + m1b[gc];
      v = 0.5f * v * (1.f + erff(v * 0.70710678118654752f));
      sH[rl * XTS + gc] = __float2bfloat16(v);
    }
  }
  __syncthreads();

  // ---- MLP2 + resid [+ stats] ----
  f32x4 acc3[2];
  {
    f32x4 z = {0.f, 0.f, 0.f, 0.f};
    acc3[0] = z;
    acc3[1] = z;
  }
#pragma unroll
  for (int k0 = 0; k0 < 128; k0 += 32) {
    short8 af = *(const short8*)&sH[lrow * XTS + k0 + quad * 8];
    short8 bfr[2];
#pragma unroll
    for (int j = 0; j < 2; ++j)
      bfr[j] = *(const short8*)&Wm2[(wv * 32 + j * 16 + lrow) * 128 + k0 + quad * 8];
#pragma unroll
    for (int j = 0; j < 2; ++j)
      acc3[j] = __builtin_amdgcn_mfma_f32_16x16x32_bf16(af, bfr[j], acc3[j], 0, 0, 0);
  }
#pragma unroll
  for (int r = 0; r < 4; ++r) {
    int rl = quad * 4 + r;
    long gr = row0 + rl;
    float s1 = 0.f, s2 = 0.f;
#pragma unroll
    for (int j = 0; j < 2; ++j) {
      int gc = wv * 32 + j * 16 + lrow;
      float v = acc3[j][r] + m2b[gc] + jf[gr * 128 + gc];
      acc3[j][r] = v;
      jf[gr * 128 + gc] = v;
      if (QKV) {
        s1 += v;
        s2 += v * v;
      }
    }
    if (QKV) {
#pragma unroll
      for (int m = 1; m < 16; m <<= 1) {
        s1 += __shfl_xor(s1, m, 64);
        s2 += __shfl_xor(s2, m, 64);
      }
      if (lrow == 0) {
        sstat[rl][wv][0] = s1;
        sstat[rl][wv][1] = s2;
      }
    }
  }
  if (!QKV) return;
  __syncthreads();
  if (t < 16) {
    float s1 = 0.f, s2 = 0.f;
#pragma unroll
    for (int w = 0; w < 4; ++w) {
      s1 += sstat[t][w][0];
      s2 += sstat[t][w][1];
    }
    float mu = s1 * (1.f / 128.f);
    float var = s2 * (1.f / 128.f) - mu * mu;
    sstatF[t][0] = mu;
    sstatF[t][1] = rsqrtf(var + 1e-5f);
  }
  __syncthreads();
#pragma unroll
  for (int r = 0; r < 4; ++r) {
    int rl = quad * 4 + r;
    float mu = sstatF[rl][0], inv = sstatF[rl][1];
#pragma unroll
    for (int j = 0; j < 2; ++j) {
      int gc = wv * 32 + j * 16 + lrow;
      sX[rl * XTS + gc] = __float2bfloat16((acc3[j][r] - mu) * inv * g1n[gc] + b1n[gc]);
    }
  }
  __syncthreads();
  for (int p = 0; p < 3; ++p) {
    f32x4 acc4[2];
    {
      f32x4 z = {0.f, 0.f, 0.f, 0.f};
      acc4[0] = z;
      acc4[1] = z;
    }
#pragma unroll
    for (int k0 = 0; k0 < 128; k0 += 32) {
      short8 af = *(const short8*)&sX[lrow * XTS + k0 + quad * 8];
      short8 bfr[2];
#pragma unroll
      for (int j = 0; j < 2; ++j)
        bfr[j] = *(const short8*)&Wqn[(long)(p * 128 + wv * 32 + j * 16 + lrow) * 128 +
                                      k0 + quad * 8];
#pragma unroll
      for (int j = 0; j < 2; ++j)
        acc4[j] = __builtin_amdgcn_mfma_f32_16x16x32_bf16(af, bfr[j], acc4[j], 0, 0, 0);
    }
#pragma unroll
    for (int r = 0; r < 4; ++r) {
      long gr = row0 + quad * 4 + r;
#pragma unroll
      for (int j = 0; j < 2; ++j) {
        int gc = p * 128 + wv * 32 + j * 16 + lrow;
        qkvb[gr * 384 + gc] = acc4[j][r] + qbn[gc];
      }
    }
  }
}

// ---- fused attention: 4 independent waves per block, one wave per (b,h,n) ----
__global__ __launch_bounds__(256) void k_attn(const float* __restrict__ qkv,
                                              const bf16* __restrict__ aR,
                                              const float* __restrict__ conn,
                                              bf16* __restrict__ obuf) {
  __shared__ float p[4][4 * 68];
  const int wv = threadIdx.x >> 6;
  const int n = blockIdx.x * 4 + wv;
  const int h = blockIdx.y, b = blockIdx.z;
  const int lane = threadIdx.x & 63;
  const long rowq = (long)(b * Nn + n);
  const float* qp = &qkv[rowq * 384 + h * 16];
  f32x4 q0 = *(const f32x4*)qp;
  f32x4 q1 = *(const f32x4*)(qp + 4);
  f32x4 q2 = *(const f32x4*)(qp + 8);
  f32x4 q3 = *(const f32x4*)(qp + 12);
  const bf16* arp = &aR[((long)(b * Hh + h) * Nn + n) * Nn];
  const float* cnp = &conn[rowq * Nn];

  float lg[4];
#pragma unroll
  for (int s = 0; s < 4; ++s) {
    int m = s * 64 + lane;
    const float* kp = &qkv[((long)(b * Nn + m)) * 384 + 128 + h * 16];
    f32x4 k0 = *(const f32x4*)kp;
    f32x4 k1 = *(const f32x4*)(kp + 4);
    f32x4 k2 = *(const f32x4*)(kp + 8);
    f32x4 k3 = *(const f32x4*)(kp + 12);
    float d = 0.f;
#pragma unroll
    for (int e = 0; e < 4; ++e)
      d += q0[e] * k0[e] + q1[e] * k1[e] + q2[e] * k2[e] + q3[e] * k3[e];
    d += __bfloat162float(arp[m]);
    lg[s] = d * cnp[m] * 0.25f;
  }
  float mx = fmaxf(fmaxf(lg[0], lg[1]), fmaxf(lg[2], lg[3]));
#pragma unroll
  for (int off = 32; off; off >>= 1) mx = fmaxf(mx, __shfl_xor(mx, off, 64));
  float ex[4], ssum = 0.f;
#pragma unroll
  for (int s = 0; s < 4; ++s) {
    ex[s] = expf(lg[s] - mx);
    ssum += ex[s];
  }
#pragma unroll
  for (int off = 32; off; off >>= 1) ssum += __shfl_xor(ssum, off, 64);
#pragma unroll
  for (int s = 0; s < 4; ++s) p[wv][s * 68 + lane] = ex[s];
  float rinv = 1.f / ssum;

  const int c = lane & 15, sg = lane >> 4;
  const float* vp = &qkv[((long)(b * Nn + sg * 64)) * 384 + 256 + h * 16 + c];
  float acc = 0.f;
#pragma unroll
  for (int u = 0; u < 16; ++u) {
    f32x4 pq = *(const f32x4*)&p[wv][sg * 68 + u * 4];
#pragma unroll
    for (int e = 0; e < 4; ++e) acc += pq[e] * vp[(long)(u * 4 + e) * 384];
  }
  acc += __shfl_xor(acc, 16, 64);
  acc += __shfl_xor(acc, 32, 64);
  if (lane < 16) obuf[rowq * 128 + h * 16 + lane] = __float2bfloat16(acc * rinv);
}

extern "C" void kernel_launch(void* const* d_in, const int* in_sizes, int n_in,
                              void* d_out, int out_size, void* d_ws, size_t ws_size,
                              hipStream_t stream) {
  const float* joint_in = (const float*)d_in[0];
  const float* relation_in = (const float*)d_in[1];
  const float* conn = (const float*)d_in[2];
  const float* je_w1 = (const float*)d_in[3];
  const float* je_b1 = (const float*)d_in[4];
  const float* je_w2 = (const float*)d_in[5];
  const float* je_b2 = (const float*)d_in[6];
  const float* je_w3 = (const float*)d_in[7];
  const float* je_b3 = (const float*)d_in[8];
  const float* re_w1 = (const float*)d_in[9];
  const float* re_b1 = (const float*)d_in[10];
  const float* re_w2 = (const float*)d_in[11];
  const float* re_b2 = (const float*)d_in[12];
  const float* re_w3 = (const float*)d_in[13];
  const float* re_b3 = (const float*)d_in[14];
  const float* qkv_w = (const float*)d_in[15];
  const float* qkv_b = (const float*)d_in[16];
  const float* rconv_w = (const float*)d_in[17];
  const float* rconv_b = (const float*)d_in[18];
  const float* proj_w = (const float*)d_in[19];
  const float* proj_b = (const float*)d_in[20];
  const float* ln1_g = (const float*)d_in[21];
  const float* ln1_b = (const float*)d_in[22];
  const float* ln2_g = (const float*)d_in[23];
  const float* ln2_b = (const float*)d_in[24];
  const float* ln3_g = (const float*)d_in[25];
  const float* ln3_b = (const float*)d_in[26];
  const float* mw1 = (const float*)d_in[27];
  const float* mb1 = (const float*)d_in[28];
  const float* mw2 = (const float*)d_in[29];
  const float* mb2 = (const float*)d_in[30];
  const float* ng = (const float*)d_in[31];
  const float* nb = (const float*)d_in[32];
  const float* dw1 = (const float*)d_in[33];
  const float* db1 = (const float*)d_in[34];
  const float* dw2 = (const float*)d_in[35];
  const float* db2 = (const float*)d_in[36];
  const float* dw3 = (const float*)d_in[37];
  const float* db3 = (const float*)d_in[38];

  char* ws = (char*)d_ws;
  size_t off = 0;
  auto alloc = [&](size_t bytes) -> void* {
    void* p = ws + off;
    off += (bytes + 255) & ~(size_t)255;
    return p;
  };
  bf16* attnR = (bf16*)alloc((size_t)DEPTHd * Bb * Hh * Nn * Nn * 2);
  bf16* gWt = (bf16*)alloc(32 * 128 * 2);
  float* sgW = (float*)alloc(32 * 4);
  float* bconst = (float*)alloc(32 * 4);
  bf16* Wq = (bf16*)alloc(4 * 384 * 128 * 2);
  bf16* Wp = (bf16*)alloc(4 * 128 * 128 * 2);
  bf16* Wm1 = (bf16*)alloc(4 * 128 * 128 * 2);
  bf16* Wm2 = (bf16*)alloc(4 * 128 * 128 * 2);
  bf16* W123t = (bf16*)alloc(128 * 32 * 2);
  float* b123 = (float*)alloc(128 * 4);
  bf16* Wj123t = (bf16*)alloc(128 * 96 * 2);
  float* bj123 = (float*)alloc(128 * 4);
  bf16* Wd123t = (bf16*)alloc(128 * 128 * 2);
  float* bd123p = (float*)alloc(128 * 4);
  float* F = (float*)alloc(26 * 256 * 4);
  float* bT = (float*)alloc(256 * 4);
  float* Fj = (float*)alloc(96 * 256 * 4);
  float* bTj = (float*)alloc(256 * 4);
  float* G = (float*)alloc(256 * 90 * 4);
  float* u1 = (float*)alloc(512 * 4);
  float* jf = (float*)alloc((size_t)BN * 128 * 4);
  bf16* obuf = (bf16*)alloc((size_t)BN * 128 * 2);
  char* U = (char*)alloc((size_t)BN * 384 * 4);
  float* qkvb = (float*)U;

  // stage-A folds + transposes
  k_prep0<<<dim3(256), dim3(256), 0, stream>>>(
      re_w1, re_w2, re_b1, re_b2, je_w1, je_w2, je_b1, je_b2, dw2, dw3, db1,
      ln2_g, ln2_b, rconv_w, rconv_b, qkv_w, proj_w, mw1, mw2,
      F, bT, Fj, bTj, G, u1, gWt, sgW, bconst, Wq, Wp, Wm1, Wm2);
  // stage-B folds
  k_prep1<<<dim3(64), dim3(256), 0, stream>>>(
      F, bT, re_w3, re_b3, Fj, bTj, je_w3, je_b3, dw1, G, u1, db2, dw3, db3,
      W123t, b123, Wj123t, bj123, Wd123t, bd123p);

  // folded relation encoder (attnR) + joint encoder (jf)
  k_relF<<<dim3(RELB + JB), dim3(256), 0, stream>>>(
      relation_in, W123t, b123, gWt, sgW, bconst, attnR, joint_in, Wj123t, bj123, jf);

  // depth 0 QKV
  k_lnqkv<float><<<dim3(3, 64), dim3(256), 0, stream>>>(
      jf, ln1_g, ln1_b, Wq, qkv_b, qkvb, 384, 384);

  for (int d = 0; d < DEPTHd; ++d) {
    k_attn<<<dim3(Nn / 4, Hh, Bb), dim3(256), 0, stream>>>(
        qkvb, attnR + (size_t)d * Bb * Hh * Nn * Nn, conn, obuf);
    if (d < 3) {
      k_tailq<true><<<dim3(128), dim3(256), 0, stream>>>(
          obuf, jf, Wp + (size_t)d * 16384, proj_b + d * 128, ln3_g + d * 128,
          ln3_b + d * 128, Wm1 + (size_t)d * 16384, mb1 + d * 128,
          Wm2 + (size_t)d * 16384, mb2 + d * 128, ln1_g + (d + 1) * 128,
          ln1_b + (d + 1) * 128, Wq + (size_t)(d + 1) * 49152, qkv_b + (d + 1) * 384,
          qkvb);
    } else {
      k_tailq<false><<<dim3(128), dim3(256), 0, stream>>>(
          obuf, jf, Wp + (size_t)d * 16384, proj_b + d * 128, ln3_g + d * 128,
          ln3_b + d * 128, Wm1 + (size_t)d * 16384, mb1 + d * 128,
          Wm2 + (size_t)d * 16384, mb2 + d * 128, nullptr, nullptr, nullptr, nullptr,
          nullptr);
    }
  }

  // folded final LN + decoder (one K=128 GEMM -> 90 cols)
  k_lnqkv<float><<<dim3(1, 64), dim3(256), 0, stream>>>(
      jf, ng, nb, Wd123t, bd123p, (float*)d_out, 90, 90);
}

// Round 12
// 526.798 us; speedup vs baseline: 1.3170x; 1.1645x over previous
//
#include <hip/hip_runtime.h>
#include <hip/hip_bf16.h>
#include <math.h>

typedef __hip_bfloat16 bf16;
typedef __attribute__((ext_vector_type(8))) short short8;
typedef __attribute__((ext_vector_type(4))) short s16x4;
typedef __attribute__((ext_vector_type(4))) float f32x4;
typedef __attribute__((ext_vector_type(2))) float f32x2;

#define Bb 8
#define Nn 256
#define Hh 8
#define DEPTHd 4
#define BN 2048
#define RTOT 524288
#define RELB 8192          // RTOT/64 relation blocks
#define JB 32              // BN/64 joint blocks
#define PREPB 64           // transpose tail blocks riding k_relF
#define XTS 136
#define X3S 136

__device__ inline float toF(float v) { return v; }
__device__ inline float toF(bf16 v) { return __bfloat162float(v); }
__device__ inline void stF(float* p, float v) { *p = v; }
__device__ inline void stF(bf16* p, float v) { *p = __float2bfloat16(v); }

// =============== k_relF: FOLDED relation + joint encoders + transpose tail ===============
// _mlp_stack is identity-activation -> encoders fold to single GEMMs (R11, proven).
// Blocks [0,RELB): relation -> attnR (K=32 GEMM + LN-fold 1x1conv epilogue).
// [RELB,RELB+JB): joint -> jf (K=96 GEMM).
// [RELB+JB,..+PREPB): Wq/Wp/Wm1/Wm2 transposes (consumed only after this kernel)
//   riding the dispatch shadow (R8/R10-proven pattern; R12 moves them back here
//   after R11's serial k_prep0 measured 77us at 0.9% occupancy).
__global__ __launch_bounds__(256) void k_relF(
    const float* __restrict__ rin, const bf16* __restrict__ W123t,
    const float* __restrict__ b123, const bf16* __restrict__ gWt,
    const float* __restrict__ sgW, const float* __restrict__ bconst,
    bf16* __restrict__ attnR, const float* __restrict__ jin,
    const bf16* __restrict__ Wj123t, const float* __restrict__ bj123,
    float* __restrict__ jf,
    const float* __restrict__ qkv_w, const float* __restrict__ proj_w,
    const float* __restrict__ mw1, const float* __restrict__ mw2,
    bf16* __restrict__ Wq, bf16* __restrict__ Wp, bf16* __restrict__ Wm1,
    bf16* __restrict__ Wm2) {
  const int t = threadIdx.x;

  // ---- transpose tail blocks (no LDS, no barriers; return early) ----
  if (blockIdx.x >= RELB + JB) {
    const int stride = PREPB * 256;
    const int tid = (blockIdx.x - (RELB + JB)) * 256 + t;
    for (int i = tid; i < 4 * 384 * 128; i += stride) {
      int d = i / 49152, rem = i - d * 49152;
      int n = rem >> 7, k = rem & 127;
      Wq[i] = __float2bfloat16(qkv_w[d * 49152 + k * 384 + n]);
    }
    for (int i = tid; i < 4 * 128 * 128; i += stride) {
      int d = i >> 14, rem = i & 16383;
      int n = rem >> 7, k = rem & 127;
      Wp[i] = __float2bfloat16(proj_w[d * 16384 + k * 128 + n]);
      Wm1[i] = __float2bfloat16(mw1[d * 16384 + k * 128 + n]);
      Wm2[i] = __float2bfloat16(mw2[d * 16384 + k * 128 + n]);
    }
    return;
  }

  __shared__ __align__(16) char smem[17920];
  bf16* x3 = (bf16*)smem;               // [64][136] = 17408
  float* sstatF = (float*)(smem + 17408);  // [64][2] = 512

  const int lane = t & 63, wv = t >> 6;
  const int lrow = lane & 15, quad = lane >> 4;
  const bool rel = blockIdx.x < RELB;

  if (!rel) {
    // ---- joint: jf = jin @ Wj123 + bj123 (K=96, 128 cols) ----
    const long r0j = (long)(blockIdx.x - RELB) * 64;
    const long gj = r0j + wv * 16 + lrow;
    short8 aj[3];
#pragma unroll
    for (int ks = 0; ks < 3; ++ks) {
      const float* ap = &jin[gj * 96 + ks * 32 + quad * 8];
      f32x4 f0 = *(const f32x4*)ap;
      f32x4 f1 = *(const f32x4*)(ap + 4);
      bf16 pk[8];
#pragma unroll
      for (int u = 0; u < 4; ++u) {
        pk[u] = __float2bfloat16(f0[u]);
        pk[u + 4] = __float2bfloat16(f1[u]);
      }
      aj[ks] = *(short8*)pk;
    }
#pragma unroll
    for (int cb = 0; cb < 4; ++cb)
#pragma unroll
      for (int ct = 0; ct < 2; ++ct) {
        int colb = cb * 32 + ct * 16;
        f32x4 x = {0.f, 0.f, 0.f, 0.f};
#pragma unroll
        for (int ks = 0; ks < 3; ++ks) {
          short8 bw = *(const short8*)&Wj123t[(colb + lrow) * 96 + ks * 32 + quad * 8];
          x = __builtin_amdgcn_mfma_f32_16x16x32_bf16(bw, aj[ks], x, 0, 0, 0);
        }
        f32x4 bq = *(const f32x4*)&bj123[colb + quad * 4];
        f32x4 out;
#pragma unroll
        for (int r = 0; r < 4; ++r) out[r] = x[r] + bq[r];
        *(f32x4*)&jf[gj * 128 + colb + quad * 4] = out;
      }
    return;
  }

  // ---- rel: y = rin @ W123 + b123 (K=32, 128 cols) -> LN-fold 1x1conv ----
  short8 a0;
  {
    const long gr = (long)blockIdx.x * 64 + wv * 16 + lrow;
    const float* ap = &rin[gr * 26];
    float v[8];
    if (quad < 3) {
#pragma unroll
      for (int u = 0; u < 4; ++u) {
        f32x2 f = *(const f32x2*)(ap + quad * 8 + u * 2);
        v[u * 2] = f[0];
        v[u * 2 + 1] = f[1];
      }
    } else {
      f32x2 f = *(const f32x2*)(ap + 24);
      v[0] = f[0];
      v[1] = f[1];
#pragma unroll
      for (int u = 2; u < 8; ++u) v[u] = 0.f;
    }
    bf16 pk[8];
#pragma unroll
    for (int u = 0; u < 8; ++u) pk[u] = __float2bfloat16(v[u]);
    a0 = *(short8*)pk;
  }

  float s1 = 0.f, s2 = 0.f;
#pragma unroll
  for (int cb = 0; cb < 4; ++cb)
#pragma unroll
    for (int ct = 0; ct < 2; ++ct) {
      int colb = cb * 32 + ct * 16;
      f32x4 x = {0.f, 0.f, 0.f, 0.f};
      short8 bw = *(const short8*)&W123t[(colb + lrow) * 32 + quad * 8];
      x = __builtin_amdgcn_mfma_f32_16x16x32_bf16(bw, a0, x, 0, 0, 0);
      f32x4 bq = *(const f32x4*)&b123[colb + quad * 4];
      bf16 pk[4];
#pragma unroll
      for (int r = 0; r < 4; ++r) {
        float v = x[r] + bq[r];
        pk[r] = __float2bfloat16(v);
        s1 += v;
        s2 += v * v;
      }
      *(s16x4*)&x3[(wv * 16 + lrow) * X3S + colb + quad * 4] = *(s16x4*)pk;
    }
  s1 += __shfl_xor(s1, 16, 64);
  s2 += __shfl_xor(s2, 16, 64);
  s1 += __shfl_xor(s1, 32, 64);
  s2 += __shfl_xor(s2, 32, 64);
  if (quad == 0) {
    int row = wv * 16 + lrow;
    float mu = s1 * (1.f / 128.f);
    float var = s2 * (1.f / 128.f) - mu * mu;
    sstatF[row * 2] = mu;
    sstatF[row * 2 + 1] = rsqrtf(var + 1e-5f);
  }
  short8 aw0[4], aw1[4];
#pragma unroll
  for (int kk = 0; kk < 4; ++kk) {
    aw0[kk] = *(const short8*)&gWt[lrow * 128 + kk * 32 + quad * 8];
    aw1[kk] = *(const short8*)&gWt[(16 + lrow) * 128 + kk * 32 + quad * 8];
  }
  __syncthreads();

  // ---- gemm32: 32 out-chans x 64 rows (wave = 16 rows), LN stats trick, scatter ----
  {
    f32x4 ac0 = {0.f, 0.f, 0.f, 0.f}, ac1 = {0.f, 0.f, 0.f, 0.f};
#pragma unroll
    for (int kk = 0; kk < 4; ++kk) {
      short8 bbx = *(const short8*)&x3[(wv * 16 + lrow) * X3S + kk * 32 + quad * 8];
      ac0 = __builtin_amdgcn_mfma_f32_16x16x32_bf16(aw0[kk], bbx, ac0, 0, 0, 0);
      ac1 = __builtin_amdgcn_mfma_f32_16x16x32_bf16(aw1[kk], bbx, ac1, 0, 0, 0);
    }
    const long r0 = (long)blockIdx.x * 64;
    int drow = wv * 16 + lrow;
    long gr = r0 + drow;
    float mu = sstatF[drow * 2], inv = sstatF[drow * 2 + 1];
    int bb_ = (int)(gr >> 16);
    int nn = (int)((gr >> 8) & 255);
    int mm = (int)(gr & 255);
#pragma unroll
    for (int mt = 0; mt < 2; ++mt) {
      f32x4 a = mt ? ac1 : ac0;
#pragma unroll
      for (int reg = 0; reg < 4; ++reg) {
        int col = mt * 16 + quad * 4 + reg;
        float v = inv * (a[reg] - mu * sgW[col]) + bconst[col];
        int dd = col >> 3, hh = col & 7;
        attnR[((((long)dd * Bb + bb_) * Hh + hh) * Nn + nn) * Nn + mm] =
            __float2bfloat16(v);
      }
    }
  }
}

// =============== k_prepA: stage-A folds, block-range partitioned for TLP ===============
// R12: R11's grid-stride k_prep0 chained several 256-512-deep dot products per
// THREAD (77us @ 0.9% occupancy). Here each fold gets its own block range so all
// loops run concurrently; streamed matrix read coalesced, stationary row broadcast.
__global__ __launch_bounds__(256) void k_prepA(
    const float* re_w1, const float* re_w2, const float* re_b1, const float* re_b2,
    const float* je_w1, const float* je_w2, const float* je_b1, const float* je_b2,
    const float* dw2, const float* dw3, const float* db1, const float* ln2_g,
    const float* ln2_b, const float* rconv_w, const float* rconv_b, float* F,
    float* bT, float* Fj, float* bTj, float* G, float* u1, bf16* gWt, float* sgW,
    float* bconst) {
  const int b = blockIdx.x, t = threadIdx.x;
  if (b < 26) {  // F[k][d] = sum_c re_w1[k][c] * re_w2[c][d]
    int k = b, d = t;
    float v = 0.f;
    for (int c = 0; c < 256; ++c) v += re_w1[k * 256 + c] * re_w2[c * 256 + d];
    F[k * 256 + d] = v;
  } else if (b == 26) {  // bT
    int d = t;
    float v = 0.f;
    for (int c = 0; c < 256; ++c) v += re_b1[c] * re_w2[c * 256 + d];
    bT[d] = v + re_b2[d];
  } else if (b < 123) {  // Fj[k][d], k = b-27
    int k = b - 27, d = t;
    float v = 0.f;
    for (int c = 0; c < 256; ++c) v += je_w1[k * 256 + c] * je_w2[c * 256 + d];
    Fj[k * 256 + d] = v;
  } else if (b == 123) {  // bTj
    int d = t;
    float v = 0.f;
    for (int c = 0; c < 256; ++c) v += je_b1[c] * je_w2[c * 256 + d];
    bTj[d] = v + je_b2[d];
  } else if (b < 380) {  // G[c][m] = sum_d dw2[c][d] * dw3[d][m], c = b-124
    int c = b - 124, m = t;
    if (m < 90) {
      float v = 0.f;
      for (int d = 0; d < 512; ++d) v += dw2[c * 512 + d] * dw3[d * 90 + m];
      G[c * 90 + m] = v;
    }
  } else if (b == 380) {  // u1[i] = sum_c db1[c] * dw2[c][i]
    for (int i = t; i < 512; i += 256) {
      float v = 0.f;
      for (int c = 0; c < 256; ++c) v += db1[c] * dw2[c * 512 + i];
      u1[i] = v;
    }
  } else if (b < 397) {  // gWt (4096 elements, 16 blocks)
    int i = (b - 381) * 256 + t;
    int col = i >> 7, c = i & 127;
    int dd = col >> 3, h = col & 7;
    gWt[i] = __float2bfloat16(ln2_g[dd * 128 + c] * rconv_w[(dd * 128 + c) * 8 + h]);
  } else {  // sgW / bconst
    if (t < 32) {
      int dd = t >> 3, h = t & 7;
      float sg = 0.f, bc = 0.f;
      for (int c = 0; c < 128; ++c) {
        float w = rconv_w[(dd * 128 + c) * 8 + h];
        sg += ln2_g[dd * 128 + c] * w;
        bc += ln2_b[dd * 128 + c] * w;
      }
      sgW[t] = sg;
      bconst[t] = bc + rconv_b[t];
    }
  }
}

// =============== k_prepB: stage-B folds (block=k, thread=m -> coalesced reads) ===============
__global__ __launch_bounds__(256) void k_prepB(
    const float* F, const float* bT, const float* re_w3, const float* re_b3,
    const float* Fj, const float* bTj, const float* je_w3, const float* je_b3,
    const float* dw1, const float* G, const float* u1, const float* db2,
    const float* dw3, const float* db3, bf16* W123t, float* b123, bf16* Wj123t,
    float* bj123, bf16* Wd123t, float* bd123p) {
  const int b = blockIdx.x, t = threadIdx.x;
  if (b < 32) {  // W123t[m][k], k = b (zero for k >= 26)
    if (t < 128) {
      int k = b, m = t;
      float v = 0.f;
      if (k < 26)
        for (int d = 0; d < 256; ++d) v += F[k * 256 + d] * re_w3[d * 128 + m];
      W123t[m * 32 + k] = __float2bfloat16(v);
    }
  } else if (b == 32) {  // b123
    if (t < 128) {
      float v = 0.f;
      for (int d = 0; d < 256; ++d) v += bT[d] * re_w3[d * 128 + t];
      b123[t] = v + re_b3[t];
    }
  } else if (b < 129) {  // Wj123t[m][k], k = b-33
    if (t < 128) {
      int k = b - 33, m = t;
      float v = 0.f;
      for (int d = 0; d < 256; ++d) v += Fj[k * 256 + d] * je_w3[d * 128 + m];
      Wj123t[m * 96 + k] = __float2bfloat16(v);
    }
  } else if (b == 129) {  // bj123
    if (t < 128) {
      float v = 0.f;
      for (int d = 0; d < 256; ++d) v += bTj[d] * je_w3[d * 128 + t];
      bj123[t] = v + je_b3[t];
    }
  } else if (b < 258) {  // Wd123t[m][k], k = b-130 (zero for m >= 90)
    if (t < 128) {
      int k = b - 130, m = t;
      float v = 0.f;
      if (m < 90)
        for (int c = 0; c < 256; ++c) v += dw1[k * 256 + c] * G[c * 90 + m];
      Wd123t[m * 128 + k] = __float2bfloat16(v);
    }
  } else {  // bd123p
    if (t < 128) {
      float v = 0.f;
      if (t < 90) {
        for (int d = 0; d < 512; ++d) v += (u1[d] + db2[d]) * dw3[d * 90 + t];
        v += db3[t];
      }
      bd123p[t] = v;
    }
  }
}

// =============== k_lnqkv: row-LN (dim 128) fused into K=128 GEMM, 32-row blocks ===============
template <typename TC>
__global__ __launch_bounds__(256) void k_lnqkv(
    const float* __restrict__ A, const float* __restrict__ g,
    const float* __restrict__ b, const bf16* __restrict__ Bt,
    const float* __restrict__ bias, TC* __restrict__ C, int ldc, int ncols) {
  __shared__ __align__(16) bf16 sX[32 * XTS];
  const int t = threadIdx.x;
  const int lane = t & 63;
  const int wv = t >> 6;
  const int lrow = lane & 15, quad = lane >> 4;
  const long row0 = (long)blockIdx.y * 32;
  const int n0 = blockIdx.x * 128;

  {
    int row = t >> 3, prt = t & 7;
    const float* ap = &A[(row0 + row) * 128 + prt * 16];
    float v[16];
    float s1 = 0.f, s2 = 0.f;
#pragma unroll
    for (int u = 0; u < 4; ++u) {
      f32x4 q = *(const f32x4*)(ap + u * 4);
#pragma unroll
      for (int e = 0; e < 4; ++e) {
        v[u * 4 + e] = q[e];
        s1 += q[e];
        s2 += q[e] * q[e];
      }
    }
    s1 += __shfl_xor(s1, 1, 64);
    s2 += __shfl_xor(s2, 1, 64);
    s1 += __shfl_xor(s1, 2, 64);
    s2 += __shfl_xor(s2, 2, 64);
    s1 += __shfl_xor(s1, 4, 64);
    s2 += __shfl_xor(s2, 4, 64);
    float mu = s1 * (1.f / 128.f);
    float inv = rsqrtf(s2 * (1.f / 128.f) - mu * mu + 1e-5f);
#pragma unroll
    for (int u4 = 0; u4 < 4; ++u4) {
      bf16 pk[4];
#pragma unroll
      for (int e = 0; e < 4; ++e) {
        int c = prt * 16 + u4 * 4 + e;
        pk[e] = __float2bfloat16((v[u4 * 4 + e] - mu) * inv * g[c] + b[c]);
      }
      *(s16x4*)&sX[row * XTS + prt * 16 + u4 * 4] = *(s16x4*)pk;
    }
  }
  __syncthreads();

  f32x4 acc[2][2];
#pragma unroll
  for (int i = 0; i < 2; ++i)
#pragma unroll
    for (int j = 0; j < 2; ++j) {
      f32x4 z = {0.f, 0.f, 0.f, 0.f};
      acc[i][j] = z;
    }
#pragma unroll
  for (int k0 = 0; k0 < 128; k0 += 32) {
    short8 af[2], bfr[2];
#pragma unroll
    for (int j = 0; j < 2; ++j)
      bfr[j] = *(const short8*)&Bt[(long)(n0 + wv * 32 + j * 16 + lrow) * 128 + k0 +
                                   quad * 8];
#pragma unroll
    for (int i = 0; i < 2; ++i)
      af[i] = *(const short8*)&sX[(i * 16 + lrow) * XTS + k0 + quad * 8];
#pragma unroll
    for (int i = 0; i < 2; ++i)
#pragma unroll
      for (int j = 0; j < 2; ++j)
        acc[i][j] =
            __builtin_amdgcn_mfma_f32_16x16x32_bf16(af[i], bfr[j], acc[i][j], 0, 0, 0);
  }
#pragma unroll
  for (int i = 0; i < 2; ++i) {
#pragma unroll
    for (int r = 0; r < 4; ++r) {
      long gr = row0 + i * 16 + quad * 4 + r;
#pragma unroll
      for (int j = 0; j < 2; ++j) {
        int gc = n0 + wv * 32 + j * 16 + lrow;
        if (gc < ncols) stF(&C[gr * (long)ldc + gc], acc[i][j][r] + bias[gc]);
      }
    }
  }
}

// =============== k_tailq: proj+resid -> LN3 -> MLP(+gelu) -> resid [-> LN1' + QKV'] ===============
// 16-row blocks (grid 128).
template <bool QKV>
__global__ __launch_bounds__(256) void k_tailq(
    const bf16* __restrict__ obuf, float* __restrict__ jf, const bf16* __restrict__ Wp,
    const float* __restrict__ pb, const float* __restrict__ g3,
    const float* __restrict__ b3, const bf16* __restrict__ Wm1,
    const float* __restrict__ m1b, const bf16* __restrict__ Wm2,
    const float* __restrict__ m2b, const float* __restrict__ g1n,
    const float* __restrict__ b1n, const bf16* __restrict__ Wqn,
    const float* __restrict__ qbn, float* __restrict__ qkvb) {
  __shared__ __align__(16) bf16 sX[16 * XTS];
  __shared__ __align__(16) bf16 sH[16 * XTS];
  __shared__ float sstat[16][4][2];
  __shared__ float sstatF[16][2];

  const int t = threadIdx.x;
  const int lane = t & 63;
  const int wv = t >> 6;
  const int lrow = lane & 15, quad = lane >> 4;
  const long row0 = (long)blockIdx.x * 16;

  {
    int r = t >> 4, c8 = (t & 15) * 8;
    *(uint4*)&sX[r * XTS + c8] = *(const uint4*)&obuf[(row0 + r) * 128 + c8];
  }
  __syncthreads();

  // ---- proj GEMM (16x128, K=128), wave n-split 32 ----
  f32x4 acc[2];
  {
    f32x4 z = {0.f, 0.f, 0.f, 0.f};
    acc[0] = z;
    acc[1] = z;
  }
#pragma unroll
  for (int k0 = 0; k0 < 128; k0 += 32) {
    short8 af = *(const short8*)&sX[lrow * XTS + k0 + quad * 8];
    short8 bfr[2];
#pragma unroll
    for (int j = 0; j < 2; ++j)
      bfr[j] = *(const short8*)&Wp[(wv * 32 + j * 16 + lrow) * 128 + k0 + quad * 8];
#pragma unroll
    for (int j = 0; j < 2; ++j)
      acc[j] = __builtin_amdgcn_mfma_f32_16x16x32_bf16(af, bfr[j], acc[j], 0, 0, 0);
  }
#pragma unroll
  for (int r = 0; r < 4; ++r) {
    int rl = quad * 4 + r;
    long gr = row0 + rl;
    float s1 = 0.f, s2 = 0.f;
#pragma unroll
    for (int j = 0; j < 2; ++j) {
      int gc = wv * 32 + j * 16 + lrow;
      float v = acc[j][r] + pb[gc] + jf[gr * 128 + gc];
      acc[j][r] = v;
      jf[gr * 128 + gc] = v;
      s1 += v;
      s2 += v * v;
    }
#pragma unroll
    for (int m = 1; m < 16; m <<= 1) {
      s1 += __shfl_xor(s1, m, 64);
      s2 += __shfl_xor(s2, m, 64);
    }
    if (lrow == 0) {
      sstat[rl][wv][0] = s1;
      sstat[rl][wv][1] = s2;
    }
  }
  __syncthreads();
  if (t < 16) {
    float s1 = 0.f, s2 = 0.f;
#pragma unroll
    for (int w = 0; w < 4; ++w) {
      s1 += sstat[t][w][0];
      s2 += sstat[t][w][1];
    }
    float mu = s1 * (1.f / 128.f);
    float var = s2 * (1.f / 128.f) - mu * mu;
    sstatF[t][0] = mu;
    sstatF[t][1] = rsqrtf(var + 1e-5f);
  }
  __syncthreads();
#pragma unroll
  for (int r = 0; r < 4; ++r) {
    int rl = quad * 4 + r;
    float mu = sstatF[rl][0], inv = sstatF[rl][1];
#pragma unroll
    for (int j = 0; j < 2; ++j) {
      int gc = wv * 32 + j * 16 + lrow;
      sX[rl * XTS + gc] = __float2bfloat16((acc[j][r] - mu) * inv * g3[gc] + b3[gc]);
    }
  }
  __syncthreads();

  // ---- MLP1 + gelu ----
  f32x4 acc2[2];
  {
    f32x4 z = {0.f, 0.f, 0.f, 0.f};
    acc2[0] = z;
    acc2[1] = z;
  }
#pragma unroll
  for (int k0 = 0; k0 < 128; k0 += 32) {
    short8 af = *(const short8*)&sX[lrow * XTS + k0 + quad * 8];
    short8 bfr[2];
#pragma unroll
    for (int j = 0; j < 2; ++j)
      bfr[j] = *(const short8*)&Wm1[(wv * 32 + j * 16 + lrow) * 128 + k0 + quad * 8];
#pragma unroll
    for (int j = 0; j < 2; ++j)
      acc2[j] = __builtin_amdgcn_mfma_f32_16x16x32_bf16(af, bfr[j], acc2[j], 0, 0, 0);
  }
#pragma unroll
  for (int r = 0; r < 4; ++r) {
    int rl = quad * 4 + r;
#pragma unroll
    for (int j = 0; j < 2; ++j) {
      int gc = wv * 32 + j * 16 + lrow;
      float v = acc2[j][r] + m1b[gc];
      v = 0.5f * v * (1.f + erff(v * 0.70710678118654752f));
      sH[rl * XTS + gc] = __float2bfloat16(v);
    }
  }
  __syncthreads();

  // ---- MLP2 + resid [+ stats] ----
  f32x4 acc3[2];
  {
    f32x4 z = {0.f, 0.f, 0.f, 0.f};
    acc3[0] = z;
    acc3[1] = z;
  }
#pragma unroll
  for (int k0 = 0; k0 < 128; k0 += 32) {
    short8 af = *(const short8*)&sH[lrow * XTS + k0 + quad * 8];
    short8 bfr[2];
#pragma unroll
    for (int j = 0; j < 2; ++j)
      bfr[j] = *(const short8*)&Wm2[(wv * 32 + j * 16 + lrow) * 128 + k0 + quad * 8];
#pragma unroll
    for (int j = 0; j < 2; ++j)
      acc3[j] = __builtin_amdgcn_mfma_f32_16x16x32_bf16(af, bfr[j], acc3[j], 0, 0, 0);
  }
#pragma unroll
  for (int r = 0; r < 4; ++r) {
    int rl = quad * 4 + r;
    long gr = row0 + rl;
    float s1 = 0.f, s2 = 0.f;
#pragma unroll
    for (int j = 0; j < 2; ++j) {
      int gc = wv * 32 + j * 16 + lrow;
      float v = acc3[j][r] + m2b[gc] + jf[gr * 128 + gc];
      acc3[j][r] = v;
      jf[gr * 128 + gc] = v;
      if (QKV) {
        s1 += v;
        s2 += v * v;
      }
    }
    if (QKV) {
#pragma unroll
      for (int m = 1; m < 16; m <<= 1) {
        s1 += __shfl_xor(s1, m, 64);
        s2 += __shfl_xor(s2, m, 64);
      }
      if (lrow == 0) {
        sstat[rl][wv][0] = s1;
        sstat[rl][wv][1] = s2;
      }
    }
  }
  if (!QKV) return;
  __syncthreads();
  if (t < 16) {
    float s1 = 0.f, s2 = 0.f;
#pragma unroll
    for (int w = 0; w < 4; ++w) {
      s1 += sstat[t][w][0];
      s2 += sstat[t][w][1];
    }
    float mu = s1 * (1.f / 128.f);
    float var = s2 * (1.f / 128.f) - mu * mu;
    sstatF[t][0] = mu;
    sstatF[t][1] = rsqrtf(var + 1e-5f);
  }
  __syncthreads();
#pragma unroll
  for (int r = 0; r < 4; ++r) {
    int rl = quad * 4 + r;
    float mu = sstatF[rl][0], inv = sstatF[rl][1];
#pragma unroll
    for (int j = 0; j < 2; ++j) {
      int gc = wv * 32 + j * 16 + lrow;
      sX[rl * XTS + gc] = __float2bfloat16((acc3[j][r] - mu) * inv * g1n[gc] + b1n[gc]);
    }
  }
  __syncthreads();
  for (int p = 0; p < 3; ++p) {
    f32x4 acc4[2];
    {
      f32x4 z = {0.f, 0.f, 0.f, 0.f};
      acc4[0] = z;
      acc4[1] = z;
    }
#pragma unroll
    for (int k0 = 0; k0 < 128; k0 += 32) {
      short8 af = *(const short8*)&sX[lrow * XTS + k0 + quad * 8];
      short8 bfr[2];
#pragma unroll
      for (int j = 0; j < 2; ++j)
        bfr[j] = *(const short8*)&Wqn[(long)(p * 128 + wv * 32 + j * 16 + lrow) * 128 +
                                      k0 + quad * 8];
#pragma unroll
      for (int j = 0; j < 2; ++j)
        acc4[j] = __builtin_amdgcn_mfma_f32_16x16x32_bf16(af, bfr[j], acc4[j], 0, 0, 0);
    }
#pragma unroll
    for (int r = 0; r < 4; ++r) {
      long gr = row0 + quad * 4 + r;
#pragma unroll
      for (int j = 0; j < 2; ++j) {
        int gc = p * 128 + wv * 32 + j * 16 + lrow;
        qkvb[gr * 384 + gc] = acc4[j][r] + qbn[gc];
      }
    }
  }
}

// ---- fused attention: 4 independent waves per block, one wave per (b,h,n) ----
__global__ __launch_bounds__(256) void k_attn(const float* __restrict__ qkv,
                                              const bf16* __restrict__ aR,
                                              const float* __restrict__ conn,
                                              bf16* __restrict__ obuf) {
  __shared__ float p[4][4 * 68];
  const int wv = threadIdx.x >> 6;
  const int n = blockIdx.x * 4 + wv;
  const int h = blockIdx.y, b = blockIdx.z;
  const int lane = threadIdx.x & 63;
  const long rowq = (long)(b * Nn + n);
  const float* qp = &qkv[rowq * 384 + h * 16];
  f32x4 q0 = *(const f32x4*)qp;
  f32x4 q1 = *(const f32x4*)(qp + 4);
  f32x4 q2 = *(const f32x4*)(qp + 8);
  f32x4 q3 = *(const f32x4*)(qp + 12);
  const bf16* arp = &aR[((long)(b * Hh + h) * Nn + n) * Nn];
  const float* cnp = &conn[rowq * Nn];

  float lg[4];
#pragma unroll
  for (int s = 0; s < 4; ++s) {
    int m = s * 64 + lane;
    const float* kp = &qkv[((long)(b * Nn + m)) * 384 + 128 + h * 16];
    f32x4 k0 = *(const f32x4*)kp;
    f32x4 k1 = *(const f32x4*)(kp + 4);
    f32x4 k2 = *(const f32x4*)(kp + 8);
    f32x4 k3 = *(const f32x4*)(kp + 12);
    float d = 0.f;
#pragma unroll
    for (int e = 0; e < 4; ++e)
      d += q0[e] * k0[e] + q1[e] * k1[e] + q2[e] * k2[e] + q3[e] * k3[e];
    d += __bfloat162float(arp[m]);
    lg[s] = d * cnp[m] * 0.25f;
  }
  float mx = fmaxf(fmaxf(lg[0], lg[1]), fmaxf(lg[2], lg[3]));
#pragma unroll
  for (int off = 32; off; off >>= 1) mx = fmaxf(mx, __shfl_xor(mx, off, 64));
  float ex[4], ssum = 0.f;
#pragma unroll
  for (int s = 0; s < 4; ++s) {
    ex[s] = expf(lg[s] - mx);
    ssum += ex[s];
  }
#pragma unroll
  for (int off = 32; off; off >>= 1) ssum += __shfl_xor(ssum, off, 64);
#pragma unroll
  for (int s = 0; s < 4; ++s) p[wv][s * 68 + lane] = ex[s];
  float rinv = 1.f / ssum;

  const int c = lane & 15, sg = lane >> 4;
  const float* vp = &qkv[((long)(b * Nn + sg * 64)) * 384 + 256 + h * 16 + c];
  float acc = 0.f;
#pragma unroll
  for (int u = 0; u < 16; ++u) {
    f32x4 pq = *(const f32x4*)&p[wv][sg * 68 + u * 4];
#pragma unroll
    for (int e = 0; e < 4; ++e) acc += pq[e] * vp[(long)(u * 4 + e) * 384];
  }
  acc += __shfl_xor(acc, 16, 64);
  acc += __shfl_xor(acc, 32, 64);
  if (lane < 16) obuf[rowq * 128 + h * 16 + lane] = __float2bfloat16(acc * rinv);
}

extern "C" void kernel_launch(void* const* d_in, const int* in_sizes, int n_in,
                              void* d_out, int out_size, void* d_ws, size_t ws_size,
                              hipStream_t stream) {
  const float* joint_in = (const float*)d_in[0];
  const float* relation_in = (const float*)d_in[1];
  const float* conn = (const float*)d_in[2];
  const float* je_w1 = (const float*)d_in[3];
  const float* je_b1 = (const float*)d_in[4];
  const float* je_w2 = (const float*)d_in[5];
  const float* je_b2 = (const float*)d_in[6];
  const float* je_w3 = (const float*)d_in[7];
  const float* je_b3 = (const float*)d_in[8];
  const float* re_w1 = (const float*)d_in[9];
  const float* re_b1 = (const float*)d_in[10];
  const float* re_w2 = (const float*)d_in[11];
  const float* re_b2 = (const float*)d_in[12];
  const float* re_w3 = (const float*)d_in[13];
  const float* re_b3 = (const float*)d_in[14];
  const float* qkv_w = (const float*)d_in[15];
  const float* qkv_b = (const float*)d_in[16];
  const float* rconv_w = (const float*)d_in[17];
  const float* rconv_b = (const float*)d_in[18];
  const float* proj_w = (const float*)d_in[19];
  const float* proj_b = (const float*)d_in[20];
  const float* ln1_g = (const float*)d_in[21];
  const float* ln1_b = (const float*)d_in[22];
  const float* ln2_g = (const float*)d_in[23];
  const float* ln2_b = (const float*)d_in[24];
  const float* ln3_g = (const float*)d_in[25];
  const float* ln3_b = (const float*)d_in[26];
  const float* mw1 = (const float*)d_in[27];
  const float* mb1 = (const float*)d_in[28];
  const float* mw2 = (const float*)d_in[29];
  const float* mb2 = (const float*)d_in[30];
  const float* ng = (const float*)d_in[31];
  const float* nb = (const float*)d_in[32];
  const float* dw1 = (const float*)d_in[33];
  const float* db1 = (const float*)d_in[34];
  const float* dw2 = (const float*)d_in[35];
  const float* db2 = (const float*)d_in[36];
  const float* dw3 = (const float*)d_in[37];
  const float* db3 = (const float*)d_in[38];

  char* ws = (char*)d_ws;
  size_t off = 0;
  auto alloc = [&](size_t bytes) -> void* {
    void* p = ws + off;
    off += (bytes + 255) & ~(size_t)255;
    return p;
  };
  bf16* attnR = (bf16*)alloc((size_t)DEPTHd * Bb * Hh * Nn * Nn * 2);
  bf16* gWt = (bf16*)alloc(32 * 128 * 2);
  float* sgW = (float*)alloc(32 * 4);
  float* bconst = (float*)alloc(32 * 4);
  bf16* Wq = (bf16*)alloc(4 * 384 * 128 * 2);
  bf16* Wp = (bf16*)alloc(4 * 128 * 128 * 2);
  bf16* Wm1 = (bf16*)alloc(4 * 128 * 128 * 2);
  bf16* Wm2 = (bf16*)alloc(4 * 128 * 128 * 2);
  bf16* W123t = (bf16*)alloc(128 * 32 * 2);
  float* b123 = (float*)alloc(128 * 4);
  bf16* Wj123t = (bf16*)alloc(128 * 96 * 2);
  float* bj123 = (float*)alloc(128 * 4);
  bf16* Wd123t = (bf16*)alloc(128 * 128 * 2);
  float* bd123p = (float*)alloc(128 * 4);
  float* F = (float*)alloc(26 * 256 * 4);
  float* bT = (float*)alloc(256 * 4);
  float* Fj = (float*)alloc(96 * 256 * 4);
  float* bTj = (float*)alloc(256 * 4);
  float* G = (float*)alloc(256 * 90 * 4);
  float* u1 = (float*)alloc(512 * 4);
  float* jf = (float*)alloc((size_t)BN * 128 * 4);
  bf16* obuf = (bf16*)alloc((size_t)BN * 128 * 2);
  char* U = (char*)alloc((size_t)BN * 384 * 4);
  float* qkvb = (float*)U;

  // stage-A folds (block-range parallel)
  k_prepA<<<dim3(398), dim3(256), 0, stream>>>(
      re_w1, re_w2, re_b1, re_b2, je_w1, je_w2, je_b1, je_b2, dw2, dw3, db1,
      ln2_g, ln2_b, rconv_w, rconv_b, F, bT, Fj, bTj, G, u1, gWt, sgW, bconst);
  // stage-B folds (coalesced: block=k, thread=m)
  k_prepB<<<dim3(259), dim3(256), 0, stream>>>(
      F, bT, re_w3, re_b3, Fj, bTj, je_w3, je_b3, dw1, G, u1, db2, dw3, db3,
      W123t, b123, Wj123t, bj123, Wd123t, bd123p);

  // folded relation encoder (attnR) + joint encoder (jf) + transpose tail
  k_relF<<<dim3(RELB + JB + PREPB), dim3(256), 0, stream>>>(
      relation_in, W123t, b123, gWt, sgW, bconst, attnR, joint_in, Wj123t, bj123, jf,
      qkv_w, proj_w, mw1, mw2, Wq, Wp, Wm1, Wm2);

  // depth 0 QKV
  k_lnqkv<float><<<dim3(3, 64), dim3(256), 0, stream>>>(
      jf, ln1_g, ln1_b, Wq, qkv_b, qkvb, 384, 384);

  for (int d = 0; d < DEPTHd; ++d) {
    k_attn<<<dim3(Nn / 4, Hh, Bb), dim3(256), 0, stream>>>(
        qkvb, attnR + (size_t)d * Bb * Hh * Nn * Nn, conn, obuf);
    if (d < 3) {
      k_tailq<true><<<dim3(128), dim3(256), 0, stream>>>(
          obuf, jf, Wp + (size_t)d * 16384, proj_b + d * 128, ln3_g + d * 128,
          ln3_b + d * 128, Wm1 + (size_t)d * 16384, mb1 + d * 128,
          Wm2 + (size_t)d * 16384, mb2 + d * 128, ln1_g + (d + 1) * 128,
          ln1_b + (d + 1) * 128, Wq + (size_t)(d + 1) * 49152, qkv_b + (d + 1) * 384,
          qkvb);
    } else {
      k_tailq<false><<<dim3(128), dim3(256), 0, stream>>>(
          obuf, jf, Wp + (size_t)d * 16384, proj_b + d * 128, ln3_g + d * 128,
          ln3_b + d * 128, Wm1 + (size_t)d * 16384, mb1 + d * 128,
          Wm2 + (size_t)d * 16384, mb2 + d * 128, nullptr, nullptr, nullptr, nullptr,
          nullptr);
    }
  }

  // folded final LN + decoder (one K=128 GEMM -> 90 cols)
  k_lnqkv<float><<<dim3(1, 64), dim3(256), 0, stream>>>(
      jf, ng, nb, Wd123t, bd123p, (float*)d_out, 90, 90);
}